// Round 1
// baseline (1163338.867 us; speedup 1.0000x reference)
//
#include <hip/hip_runtime.h>
#include <math.h>

#define D2T   16
#define CHI   96
#define NITER 12
#define KSUB  128
#define QSUB  16
#define JSW   12
#define NBRED 128

// ---------------- tiny builders ----------------
__global__ void k_symA(const float* __restrict__ A1, float* __restrict__ As) {
  int i = blockIdx.x * blockDim.x + threadIdx.x;
  if (i >= 128) return;
  int w = i % 4, x = (i / 4) % 4, u = (i / 16) % 4, p = i / 64;
#define AT(pp,aa,bb,cc) A1[(((pp)*4+(aa))*4+(bb))*4+(cc)]
  As[i] = AT(p,u,x,w) + AT(p,u,w,x) + AT(p,x,w,u) + AT(p,w,x,u) + AT(p,w,u,x) + AT(p,x,u,w);
#undef AT
}

__global__ void k_buildT(const float* __restrict__ As, float* __restrict__ T) {
  int i = blockIdx.x * blockDim.x + threadIdx.x;
  if (i >= 4096) return;
  int Wf = i % 16, Xf = (i / 16) % 16, Uf = i / 256;
  int u = Uf >> 2, a = Uf & 3, x = Xf >> 2, b = Xf & 3, w = Wf >> 2, c = Wf & 3;
  float s = 0.f;
  for (int p = 0; p < 2; ++p)
    s += As[((p*4+u)*4+x)*4+w] * As[((p*4+a)*4+b)*4+c];
  T[i] = s;
}

__global__ void k_buildM(const float* __restrict__ T, float* __restrict__ M) {
  int i = blockIdx.x * blockDim.x + threadIdx.x;
  if (i >= 65536) return;
  int y = i % 16, x = (i / 16) % 16, v = (i / 256) % 16, u = i / 4096;
  const float* Tu = T + (u*16 + x)*16;
  const float* Tv = T + (v*16 + y)*16;
  float s = 0.f;
  for (int w = 0; w < 16; ++w) s += Tu[w]*Tv[w];
  M[i] = s;
}

__global__ void k_initC(const float* __restrict__ M, float* __restrict__ C) {
  int i = blockIdx.x * blockDim.x + threadIdx.x;
  if (i >= 256) return;
  int v = i / 16, y = i % 16;
  float s = 0.f;
  for (int u = 0; u < 16; ++u)
    for (int x = 0; x < 16; ++x)
      s += M[((u*16+v)*16+x)*16+y];
  C[v*16+y] = s;
}

__global__ void k_initE(const float* __restrict__ M, float* __restrict__ E) {
  int i = blockIdx.x * blockDim.x + threadIdx.x;
  if (i >= 4096) return;
  int v = i % 16, y = (i / 16) % 16, u = i / 256;
  float s = 0.f;
  for (int x = 0; x < 16; ++x) s += M[((u*16+v)*16+x)*16+y];
  E[(u*16+y)*16+v] = s;   // E[u][y][v], chic=16
}

// ---------------- generic helpers ----------------
__global__ void k_perm4(const float* __restrict__ src, float* __restrict__ dst,
                        int d0, int d1, int d2, int d3,
                        long s0, long s1, long s2, long s3) {
  long n = (long)d0 * d1 * d2 * d3;
  for (long i = blockIdx.x * (long)blockDim.x + threadIdx.x; i < n;
       i += (long)gridDim.x * blockDim.x) {
    int i3 = (int)(i % d3); long t = i / d3;
    int i2 = (int)(t % d2); t /= d2;
    int i1 = (int)(t % d1); int i0 = (int)(t / d1);
    dst[i] = src[i0*s0 + i1*s1 + i2*s2 + i3*s3];
  }
}

__global__ void k_sym2d(float* __restrict__ A, int n) {
  long nn = (long)n * n;
  for (long i = blockIdx.x * (long)blockDim.x + threadIdx.x; i < nn;
       i += (long)gridDim.x * blockDim.x) {
    int r = (int)(i / n), c = (int)(i % n);
    if (r <= c) {
      float v = 0.5f * (A[(long)r*n + c] + A[(long)c*n + r]);
      A[(long)r*n + c] = v; A[(long)c*n + r] = v;
    }
  }
}

__global__ void k_symE(float* __restrict__ E, int chi) {
  long n = (long)chi * 16 * chi;
  for (long i = blockIdx.x * (long)blockDim.x + threadIdx.x; i < n;
       i += (long)gridDim.x * blockDim.x) {
    int b = (int)(i % chi); long t = i / chi;
    int y = (int)(t % 16); int a = (int)(t / 16);
    if (a <= b) {
      long ia = ((long)a*16 + y)*chi + b, ib = ((long)b*16 + y)*chi + a;
      float v = 0.5f * (E[ia] + E[ib]);
      E[ia] = v; E[ib] = v;
    }
  }
}

__global__ void k_sumsq(const float* __restrict__ a, long n, float* __restrict__ partial) {
  __shared__ float red[256];
  float s = 0.f;
  for (long i = blockIdx.x * 256L + threadIdx.x; i < n; i += (long)gridDim.x * 256L) {
    float v = a[i]; s += v*v;
  }
  red[threadIdx.x] = s; __syncthreads();
  for (int o = 128; o; o >>= 1) { if ((int)threadIdx.x < o) red[threadIdx.x] += red[threadIdx.x + o]; __syncthreads(); }
  if (threadIdx.x == 0) partial[blockIdx.x] = red[0];
}

__global__ void k_rsqrt_of_sum(const float* __restrict__ partial, int nb, float* __restrict__ out) {
  __shared__ float red[256];
  float s = 0.f;
  for (int i = threadIdx.x; i < nb; i += 256) s += partial[i];
  red[threadIdx.x] = s; __syncthreads();
  for (int o = 128; o; o >>= 1) { if ((int)threadIdx.x < o) red[threadIdx.x] += red[threadIdx.x + o]; __syncthreads(); }
  if (threadIdx.x == 0) out[0] = rsqrtf(red[0]);
}

__global__ void k_scale(float* __restrict__ a, long n, const float* __restrict__ sc) {
  float f = sc[0];
  for (long i = blockIdx.x * (long)blockDim.x + threadIdx.x; i < n;
       i += (long)gridDim.x * blockDim.x) a[i] *= f;
}

// ---------------- GEMMs (fp32, 64x64 tile, 256 thr, 4x4/thr) ----------------
__global__ __launch_bounds__(256) void k_gemm_nn(const float* __restrict__ A, const float* __restrict__ B,
                                                 float* __restrict__ C, int M, int N, int K) {
  __shared__ float As[16][68];
  __shared__ float Bs[16][68];
  int tid = threadIdx.x, tx = tid % 16, ty = tid / 16;
  int row0 = blockIdx.y*64, col0 = blockIdx.x*64;
  float acc[4][4] = {};
  for (int k0 = 0; k0 < K; k0 += 16) {
    for (int i = tid; i < 16*64; i += 256) {
      int c = i % 16, r = i / 16;       // A[row0+r][k0+c]
      float v = 0.f;
      if (row0 + r < M && k0 + c < K) v = A[(long)(row0+r)*K + k0 + c];
      As[c][r] = v;
    }
    for (int i = tid; i < 16*64; i += 256) {
      int c = i % 64, r = i / 64;       // B[k0+r][col0+c]
      float v = 0.f;
      if (k0 + r < K && col0 + c < N) v = B[(long)(k0+r)*N + col0 + c];
      Bs[r][c] = v;
    }
    __syncthreads();
    for (int kk = 0; kk < 16; ++kk) {
      float av[4], bv[4];
#pragma unroll
      for (int ii = 0; ii < 4; ++ii) av[ii] = As[kk][ty*4+ii];
#pragma unroll
      for (int jj = 0; jj < 4; ++jj) bv[jj] = Bs[kk][tx*4+jj];
#pragma unroll
      for (int ii = 0; ii < 4; ++ii)
#pragma unroll
        for (int jj = 0; jj < 4; ++jj) acc[ii][jj] += av[ii]*bv[jj];
    }
    __syncthreads();
  }
  for (int ii = 0; ii < 4; ++ii) {
    int r = row0 + ty*4 + ii;
    if (r >= M) continue;
    for (int jj = 0; jj < 4; ++jj) {
      int c = col0 + tx*4 + jj;
      if (c < N) C[(long)r*N + c] = acc[ii][jj];
    }
  }
}

// C = A^T B ; A is (K x M) row-major, B is (K x N) row-major
__global__ __launch_bounds__(256) void k_gemm_tn(const float* __restrict__ A, const float* __restrict__ B,
                                                 float* __restrict__ C, int M, int N, int K) {
  __shared__ float As[16][68];
  __shared__ float Bs[16][68];
  int tid = threadIdx.x, tx = tid % 16, ty = tid / 16;
  int row0 = blockIdx.y*64, col0 = blockIdx.x*64;
  float acc[4][4] = {};
  for (int k0 = 0; k0 < K; k0 += 16) {
    for (int i = tid; i < 16*64; i += 256) {
      int r = i % 64, kk = i / 64;      // A[k0+kk][row0+r]
      float v = 0.f;
      if (k0 + kk < K && row0 + r < M) v = A[(long)(k0+kk)*M + row0 + r];
      As[kk][r] = v;
    }
    for (int i = tid; i < 16*64; i += 256) {
      int c = i % 64, kk = i / 64;      // B[k0+kk][col0+c]
      float v = 0.f;
      if (k0 + kk < K && col0 + c < N) v = B[(long)(k0+kk)*N + col0 + c];
      Bs[kk][c] = v;
    }
    __syncthreads();
    for (int kk = 0; kk < 16; ++kk) {
      float av[4], bv[4];
#pragma unroll
      for (int ii = 0; ii < 4; ++ii) av[ii] = As[kk][ty*4+ii];
#pragma unroll
      for (int jj = 0; jj < 4; ++jj) bv[jj] = Bs[kk][tx*4+jj];
#pragma unroll
      for (int ii = 0; ii < 4; ++ii)
#pragma unroll
        for (int jj = 0; jj < 4; ++jj) acc[ii][jj] += av[ii]*bv[jj];
    }
    __syncthreads();
  }
  for (int ii = 0; ii < 4; ++ii) {
    int r = row0 + ty*4 + ii;
    if (r >= M) continue;
    for (int jj = 0; jj < 4; ++jj) {
      int c = col0 + tx*4 + jj;
      if (c < N) C[(long)r*N + c] = acc[ii][jj];
    }
  }
}

// C = A B^T ; A is (M x K), B is (N x K) row-major
__global__ __launch_bounds__(256) void k_gemm_nt(const float* __restrict__ A, const float* __restrict__ B,
                                                 float* __restrict__ C, int M, int N, int K) {
  __shared__ float As[16][68];
  __shared__ float Bs[16][68];
  int tid = threadIdx.x, tx = tid % 16, ty = tid / 16;
  int row0 = blockIdx.y*64, col0 = blockIdx.x*64;
  float acc[4][4] = {};
  for (int k0 = 0; k0 < K; k0 += 16) {
    for (int i = tid; i < 16*64; i += 256) {
      int kk = i % 16, r = i / 16;      // A[row0+r][k0+kk]
      float v = 0.f;
      if (row0 + r < M && k0 + kk < K) v = A[(long)(row0+r)*K + k0 + kk];
      As[kk][r] = v;
    }
    for (int i = tid; i < 16*64; i += 256) {
      int kk = i % 16, c = i / 16;      // B[col0+c][k0+kk]
      float v = 0.f;
      if (col0 + c < N && k0 + kk < K) v = B[(long)(col0+c)*K + k0 + kk];
      Bs[kk][c] = v;
    }
    __syncthreads();
    for (int kk = 0; kk < 16; ++kk) {
      float av[4], bv[4];
#pragma unroll
      for (int ii = 0; ii < 4; ++ii) av[ii] = As[kk][ty*4+ii];
#pragma unroll
      for (int jj = 0; jj < 4; ++jj) bv[jj] = Bs[kk][tx*4+jj];
#pragma unroll
      for (int ii = 0; ii < 4; ++ii)
#pragma unroll
        for (int jj = 0; jj < 4; ++jj) acc[ii][jj] += av[ii]*bv[jj];
    }
    __syncthreads();
  }
  for (int ii = 0; ii < 4; ++ii) {
    int r = row0 + ty*4 + ii;
    if (r >= M) continue;
    for (int jj = 0; jj < 4; ++jj) {
      int c = col0 + tx*4 + jj;
      if (c < N) C[(long)r*N + c] = acc[ii][jj];
    }
  }
}

// ---------------- subspace iteration pieces ----------------
__global__ void k_xinit(float* __restrict__ X, int n, unsigned seed) {
  int i = blockIdx.x * blockDim.x + threadIdx.x;
  if (i >= n) return;
  unsigned x = (unsigned)i * 2654435761u + seed;
  x ^= x >> 16; x *= 2246822519u; x ^= x >> 13; x *= 3266489917u; x ^= x >> 16;
  X[i] = (float)x * (1.0f/4294967296.0f) - 0.5f;
}

// Orthonormalize the Kdim rows (length Ndim) of Yt in place. Blocked MGS with reorth.
__global__ __launch_bounds__(1024) void k_mgs(float* __restrict__ Yt, int Kdim, int Ndim) {
  __shared__ float panel[16*1536];
  __shared__ float prev[1536];
  __shared__ float red[16];
  __shared__ float sc;
  int tid = threadIdx.x;
  int wave = tid >> 6, lane = tid & 63;
  int npanel = Kdim >> 4;
  for (int pnl = 0; pnl < npanel; ++pnl) {
    float* Prow = Yt + (long)pnl*16*Ndim;
    for (int i = tid; i < 16*Ndim; i += 1024) panel[i] = Prow[i];
    __syncthreads();
    for (int pass = 0; pass < 2; ++pass) {
      for (int jj = 0; jj < pnl*16; ++jj) {
        for (int i = tid; i < Ndim; i += 1024) prev[i] = Yt[(long)jj*Ndim + i];
        __syncthreads();
        float d = 0.f;
        float* row = panel + wave*Ndim;
        for (int r = lane; r < Ndim; r += 64) d += prev[r]*row[r];
        for (int o = 32; o; o >>= 1) d += __shfl_down(d, o);
        d = __shfl(d, 0);
        for (int r = lane; r < Ndim; r += 64) row[r] -= d*prev[r];
        __syncthreads();
      }
    }
    for (int pass = 0; pass < 2; ++pass) {
      for (int j = 0; j < 16; ++j) {
        float s = 0.f;
        for (int r = tid; r < Ndim; r += 1024) { float v = panel[j*Ndim+r]; s += v*v; }
        for (int o = 32; o; o >>= 1) s += __shfl_down(s, o);
        if (lane == 0) red[wave] = s;
        __syncthreads();
        if (tid == 0) {
          float t = 0.f;
          for (int wv2 = 0; wv2 < 16; ++wv2) t += red[wv2];
          sc = (t > 1e-36f) ? rsqrtf(t) : 0.f;
        }
        __syncthreads();
        float inv = sc;
        for (int r = tid; r < Ndim; r += 1024) panel[j*Ndim+r] *= inv;
        __syncthreads();
        int l = j + 1 + wave;
        if (l < 16) {
          float d = 0.f;
          for (int r = lane; r < Ndim; r += 64) d += panel[j*Ndim+r]*panel[l*Ndim+r];
          for (int o = 32; o; o >>= 1) d += __shfl_down(d, o);
          d = __shfl(d, 0);
          for (int r = lane; r < Ndim; r += 64) panel[l*Ndim+r] -= d*panel[j*Ndim+r];
        }
        __syncthreads();
      }
    }
    for (int i = tid; i < 16*Ndim; i += 1024) Prow[i] = panel[i];
    __syncthreads();
  }
}

// Cyclic (round-robin) Jacobi eigensolver for symmetric 128x128, LDS-resident.
__global__ __launch_bounds__(512) void k_jacobi(const float* __restrict__ Bin, float* __restrict__ Vout,
                                                float* __restrict__ wout, int sweeps) {
  const int n = KSUB;
  __shared__ float Bs[KSUB*KSUB];
  __shared__ float Vs[KSUB*KSUB];
  __shared__ float cS[64], sS[64];
  __shared__ int pS[64], qS[64];
  int tid = threadIdx.x;
  for (int i = tid; i < n*n; i += 512) { Bs[i] = Bin[i]; Vs[i] = ((i / n) == (i % n)) ? 1.f : 0.f; }
  __syncthreads();
  for (int sw = 0; sw < sweeps; ++sw) {
    for (int r = 0; r < n-1; ++r) {
      if (tid < 64) {
        int k = tid, a, b;
        if (k == 0) { a = n-1; b = r % (n-1); }
        else { a = (r + k) % (n-1); b = (r - k + (n-1)) % (n-1); }
        int p = a < b ? a : b, q = a < b ? b : a;
        float bpp = Bs[p*n+p], bqq = Bs[q*n+q], bpq = Bs[p*n+q];
        float c = 1.f, s = 0.f;
        if (bpq != 0.f) {
          float tau = (bqq - bpp) / (2.f*bpq);
          float t = (tau >= 0.f ? 1.f : -1.f) / (fabsf(tau) + sqrtf(1.f + tau*tau));
          c = rsqrtf(1.f + t*t); s = t*c;
        }
        pS[k] = p; qS[k] = q; cS[k] = c; sS[k] = s;
      }
      __syncthreads();
      // B <- J^T B J over disjoint 2x2 tile-pairs
      for (int t = tid; t < 64*64; t += 512) {
        int k1 = t >> 6, k2 = t & 63;
        int p1 = pS[k1], q1 = qS[k1]; float c1 = cS[k1], s1 = sS[k1];
        int p2 = pS[k2], q2 = qS[k2]; float c2 = cS[k2], s2 = sS[k2];
        float a = Bs[p1*n+p2], b = Bs[p1*n+q2], d = Bs[q1*n+p2], e = Bs[q1*n+q2];
        float a1 = c1*a - s1*d, b1 = c1*b - s1*e;
        float d1 = s1*a + c1*d, e1 = s1*b + c1*e;
        Bs[p1*n+p2] = c2*a1 - s2*b1; Bs[p1*n+q2] = s2*a1 + c2*b1;
        Bs[q1*n+p2] = c2*d1 - s2*e1; Bs[q1*n+q2] = s2*d1 + c2*e1;
      }
      // V <- V J
      for (int t = tid; t < 64*n; t += 512) {
        int k = t >> 7, i = t & (n-1);
        int p = pS[k], q = qS[k]; float c = cS[k], s = sS[k];
        float vp = Vs[i*n+p], vq = Vs[i*n+q];
        Vs[i*n+p] = c*vp - s*vq; Vs[i*n+q] = s*vp + c*vq;
      }
      __syncthreads();
    }
  }
  for (int i = tid; i < n; i += 512) wout[i] = Bs[i*n+i];
  for (int i = tid; i < n*n; i += 512) Vout[i] = Vs[i];
}

__global__ void k_select(const float* __restrict__ w, int n, int topk,
                         int* __restrict__ idx, float* __restrict__ ws, float* __restrict__ wsn) {
  if (threadIdx.x != 0 || blockIdx.x != 0) return;
  bool used[KSUB];
  for (int i = 0; i < n; ++i) used[i] = false;
  float ss = 0.f;
  for (int t = 0; t < topk; ++t) {
    int best = 0; float bv = -1.f;
    for (int i = 0; i < n; ++i) {
      if (used[i]) continue;
      float av = fabsf(w[i]);
      if (av > bv) { bv = av; best = i; }
    }
    used[best] = true;
    idx[t] = best; ws[t] = w[best]; ss += w[best]*w[best];
  }
  wsn[0] = sqrtf(ss);
}

__global__ void k_setC(float* __restrict__ C, const float* __restrict__ ws,
                       const float* __restrict__ wsn, int chin) {
  int i = blockIdx.x * blockDim.x + threadIdx.x;
  if (i >= chin*chin) return;
  int r = i / chin, c = i % chin;
  C[i] = (r == c) ? ws[r] / wsn[0] : 0.f;
}

__global__ void k_gather(const float* __restrict__ V, const int* __restrict__ idx,
                         float* __restrict__ Vs, int n, int topk) {
  int i = blockIdx.x * blockDim.x + threadIdx.x;
  if (i >= n*topk) return;
  int r = i / topk, a = i % topk;
  Vs[i] = V[r*n + idx[a]];
}

// ---------------- observable stage ----------------
__global__ void k_buildK(const float* __restrict__ As, float* __restrict__ K6) {
  int i = blockIdx.x * blockDim.x + threadIdx.x;
  if (i >= 1024) return;
  int y = i & 3, v = (i>>2)&3, x = (i>>4)&3, u = (i>>6)&3, s = (i>>8)&1, p = (i>>9)&1;
  float acc = 0.f;
  for (int w = 0; w < 4; ++w)
    acc += As[((p*4+u)*4+x)*4+w] * As[((s*4+v)*4+y)*4+w];
  K6[i] = acc;
}

__global__ void k_Y1(const float* __restrict__ K6, const float* __restrict__ S, float* __restrict__ Y1) {
  int i = blockIdx.x * blockDim.x + threadIdx.x;
  if (i >= 1024) return;
  int f = i & 3, e = (i>>2)&3, b = (i>>4)&3, a = (i>>6)&3, s = (i>>8)&1, p = (i>>9)&1;
  float acc = 0.f;
  for (int u = 0; u < 4; ++u)
    for (int x = 0; x < 4; ++x)
      for (int v = 0; v < 4; ++v)
        for (int y = 0; y < 4; ++y)
          acc += K6[((((p*2+s)*4+u)*4+x)*4+v)*4+y]
               * S[(((x*4+b)*16 + (v*4+e))*16 + (y*4+f))*16 + (u*4+a)];
  Y1[i] = acc;
}

__global__ void k_W16(const float* __restrict__ K6, const float* __restrict__ Y1, float* __restrict__ W) {
  int i = threadIdx.x;
  if (i >= 16) return;
  int qr = i >> 2, ps = i & 3;
  float acc = 0.f;
  for (int j = 0; j < 256; ++j) acc += K6[qr*256 + j] * Y1[ps*256 + j];
  W[i] = acc;
}

__global__ void k_final(const float* __restrict__ W, const float* __restrict__ H,
                        const float* __restrict__ Ox, const float* __restrict__ Oy,
                        const float* __restrict__ Oz, float* __restrict__ out) {
  if (threadIdx.x != 0 || blockIdx.x != 0) return;
  float Z = 0.f;
  for (int q = 0; q < 2; ++q)
    for (int r = 0; r < 2; ++r) Z += W[((q*2+r)*2+q)*2+r];
  float ln = 0.f;
  for (int i = 0; i < 16; ++i) ln += H[i]*W[i];
  out[0] = ln / Z;
  const float* Os[3] = {Ox, Oy, Oz};
  for (int k = 0; k < 3; ++k) {
    float vA = 0.f, vB = 0.f;
    for (int q = 0; q < 2; ++q)
      for (int p = 0; p < 2; ++p)
        for (int r = 0; r < 2; ++r)
          vA += Os[k][q*2+p] * W[((q*2+r)*2+p)*2+r];
    for (int q = 0; q < 2; ++q)
      for (int r = 0; r < 2; ++r)
        for (int s = 0; s < 2; ++s)
          vB += Os[k][r*2+s] * W[((q*2+r)*2+q)*2+s];
    out[1+k] = 0.5f*(vA+vB)/Z;
  }
}

// ---------------- host ----------------
static inline unsigned nb256(long n) { long b = (n + 255) / 256; return (unsigned)(b < 1 ? 1 : b); }

extern "C" void kernel_launch(void* const* d_in, const int* in_sizes, int n_in,
                              void* d_out, int out_size, void* d_ws, size_t ws_size,
                              hipStream_t stream) {
  const float* A1  = (const float*)d_in[0];
  const float* Hin = (const float*)d_in[1];
  const float* Ox  = (const float*)d_in[2];
  const float* Oy  = (const float*)d_in[3];
  const float* Oz  = (const float*)d_in[4];

  const long SZ_BIG = 1536L*1536L;
  float* p0 = (float*)d_ws;
  float* Asym = p0; p0 += 128;
  float* Tb   = p0; p0 += 4096;
  float* Mb   = p0; p0 += 65536;
  float* Mp   = p0; p0 += 65536;
  float* Mq   = p0; p0 += 65536;
  float* Ca   = p0; p0 += CHI*CHI;
  float* Cb   = p0; p0 += CHI*CHI;
  float* Ea   = p0; p0 += CHI*D2T*CHI;
  float* Eb   = p0; p0 += CHI*D2T*CHI;
  float* CE   = p0; p0 += CHI*D2T*CHI;
  float* E2   = p0; p0 += CHI*D2T*CHI;
  float* Pb   = p0; p0 += (CHI*D2T)*CHI;
  float* Xa   = p0; p0 += KSUB*(CHI*D2T);
  float* Xb   = p0; p0 += KSUB*(CHI*D2T);
  float* Bsm  = p0; p0 += KSUB*KSUB;
  float* Vsm  = p0; p0 += KSUB*KSUB;
  float* wv   = p0; p0 += KSUB;
  float* wsv  = p0; p0 += KSUB;
  float* wsn  = p0; p0 += 16;
  float* scal = p0; p0 += 16;
  float* part = p0; p0 += NBRED;
  int*   idx  = (int*)p0; p0 += KSUB;
  float* Vsel = p0; p0 += KSUB*CHI;
  float* K6   = p0; p0 += 1024;
  float* Y1   = p0; p0 += 1024;
  float* W16  = p0; p0 += 16;
  float* tb   = p0; p0 += CHI*D2T*CHI;
  float* ub   = p0; p0 += CHI*D2T*CHI;
  float* Sb   = p0; p0 += 65536;
  float* B1   = p0; p0 += SZ_BIG;
  float* B2   = p0; p0 += SZ_BIG;
  float* B3   = p0; p0 += SZ_BIG;
  if ((size_t)((char*)p0 - (char*)d_ws) > ws_size) return;

  auto normalize = [&](float* a, long n) {
    int nb = (int)((n + 255) / 256); if (nb > NBRED) nb = NBRED;
    k_sumsq<<<nb, 256, 0, stream>>>(a, n, part);
    k_rsqrt_of_sum<<<1, 256, 0, stream>>>(part, nb, scal);
    k_scale<<<nb256(n), 256, 0, stream>>>(a, n, scal);
  };
  auto gnn = [&](const float* A, const float* B, float* C, int M, int N, int K) {
    dim3 g((N+63)/64, (M+63)/64);
    k_gemm_nn<<<g, 256, 0, stream>>>(A, B, C, M, N, K);
  };
  auto gtn = [&](const float* A, const float* B, float* C, int M, int N, int K) {
    dim3 g((N+63)/64, (M+63)/64);
    k_gemm_tn<<<g, 256, 0, stream>>>(A, B, C, M, N, K);
  };
  auto gnt = [&](const float* A, const float* B, float* C, int M, int N, int K) {
    dim3 g((N+63)/64, (M+63)/64);
    k_gemm_nt<<<g, 256, 0, stream>>>(A, B, C, M, N, K);
  };

  // ---- Stage A ----
  k_symA<<<1, 128, 0, stream>>>(A1, Asym);
  k_buildT<<<16, 256, 0, stream>>>(Asym, Tb);
  normalize(Tb, 4096);
  k_buildM<<<256, 256, 0, stream>>>(Tb, Mb);
  normalize(Mb, 65536);
  k_perm4<<<256, 256, 0, stream>>>(Mb, Mp, 16,16,16,16, 16L,4096L,256L,1L);   // Mp[(x,u),(v,y)]
  k_perm4<<<256, 256, 0, stream>>>(Mb, Mq, 16,16,16,16, 4096L,16L,256L,1L);   // Mq[(u,x),(v,y)]
  k_initC<<<1, 256, 0, stream>>>(Mb, Ca);
  k_sym2d<<<1, 256, 0, stream>>>(Ca, 16);
  normalize(Ca, 256);
  k_initE<<<16, 256, 0, stream>>>(Mb, Ea);
  k_symE<<<16, 256, 0, stream>>>(Ea, 16);
  normalize(Ea, 4096);

  // ---- CTMRG iterations ----
  float* Ccur = Ca; float* Calt = Cb;
  float* Ecur = Ea; float* Ealt = Eb;
  int chic = 16;
  for (int it = 0; it < NITER; ++it) {
    int Nm = chic * D2T;
    int chin = CHI;  // min(CHI, chic*16): 96 for all iterations
    // Rho build: m[(i,v),(j,y)]
    gnn(Ccur, Ecur, CE, chic, D2T*chic, chic);                                 // CE[a,(x,i)]
    k_perm4<<<nb256((long)chic*chic*16), 256, 0, stream>>>(Ecur, E2,
        chic, chic, 16, 1, 1L, (long)16*chic, (long)chic, 0L);                 // E2[a,(j,u)]
    gtn(CE, E2, B1, 16*chic, 16*chic, chic);                                   // D1[(x,i),(j,u)]
    k_perm4<<<nb256((long)Nm*Nm), 256, 0, stream>>>(B1, B2,
        chic, chic, 16, 16, (long)16*chic, 16L, (long)chic*16*chic, 1L);       // D1p[(i,j),(x,u)]
    gnn(B2, Mp, B1, chic*chic, 256, 256);                                      // Q[(i,j),(v,y)]
    k_perm4<<<nb256((long)Nm*Nm), 256, 0, stream>>>(B1, B2,
        chic, 16, chic, 16, (long)chic*256, 16L, 256L, 1L);                    // m[(i,v),(j,y)]
    k_sym2d<<<nb256((long)Nm*Nm), 256, 0, stream>>>(B2, Nm);
    float* msym = B2;
    // Subspace iteration for top eigenpairs by |lambda|
    k_xinit<<<nb256((long)KSUB*Nm), 256, 0, stream>>>(Xa, KSUB*Nm, 0x9E3779B9u);
    float* Xc = Xa; float* Yc = Xb;
    for (int t = 0; t < QSUB; ++t) {
      gnn(Xc, msym, Yc, KSUB, Nm, Nm);      // Yt = Xt * m  (m symmetric)
      k_mgs<<<1, 1024, 0, stream>>>(Yc, KSUB, Nm);
      float* tm = Xc; Xc = Yc; Yc = tm;
    }
    gnn(Xc, msym, Yc, KSUB, Nm, Nm);        // Y2 = X m
    gnt(Yc, Xc, Bsm, KSUB, KSUB, Nm);       // B = X m X^T
    k_sym2d<<<nb256((long)KSUB*KSUB), 256, 0, stream>>>(Bsm, KSUB);
    k_jacobi<<<1, 512, 0, stream>>>(Bsm, Vsm, wv, JSW);
    k_select<<<1, 1, 0, stream>>>(wv, KSUB, chin, idx, wsv, wsn);
    k_setC<<<nb256((long)chin*chin), 256, 0, stream>>>(Calt, wsv, wsn, chin);
    k_gather<<<nb256((long)KSUB*chin), 256, 0, stream>>>(Vsm, idx, Vsel, KSUB, chin);
    gtn(Xc, Vsel, Pb, Nm, chin, KSUB);      // P (Nm x chin) = Ritz vectors
    // E update: Enew[a,y,b]
    gtn(Pb, Ecur, B1, D2T*chin, D2T*chic, chic);                               // T1[(u,a),(x,j)]
    k_perm4<<<nb256((long)D2T*chin*D2T*chic), 256, 0, stream>>>(B1, B2,
        chin, chic, 16, 16, (long)16*chic, 1L, (long)chin*16*chic, (long)chic);// T1p[(a,j),(u,x)]
    gnn(B2, Mq, B1, chin*chic, 256, 256);                                      // T2[(a,j),(v,y)]
    k_perm4<<<nb256((long)chin*chic*256), 256, 0, stream>>>(B1, B2,
        chin, 16, chic, 16, (long)chic*256, 1L, 256L, 16L);                    // T2p[(a,y),(j,v)]
    gnn(B2, Pb, Ealt, chin*D2T, chin, chic*D2T);                               // Enew[(a,y),b]
    k_symE<<<nb256((long)chin*16*chin), 256, 0, stream>>>(Ealt, chin);
    normalize(Ealt, (long)chin*16*chin);
    { float* t1 = Ccur; Ccur = Calt; Calt = t1; }
    { float* t1 = Ecur; Ecur = Ealt; Ealt = t1; }
    chic = chin;
  }

  // ---- Environment closure: S_env and observables ----
  gnn(Ccur, Ecur, tb, CHI, D2T*CHI, CHI);                   // t[a,(x,c)]
  gnn(tb, Ccur, ub, CHI*D2T, CHI, CHI);                     // up[(a,x),d]
  gnn(ub, Ecur, B1, CHI*D2T, D2T*CHI, CHI);                 // T1env[(a,x),(v,e)]
  k_perm4<<<nb256(SZ_BIG), 256, 0, stream>>>(B1, B2,
      16, 16, CHI, CHI, 1536L, 96L, 24576L, 1L);            // A'[(X,V),(a,e)]
  k_perm4<<<nb256(SZ_BIG), 256, 0, stream>>>(B1, B3,
      CHI, CHI, 16, 16, 1L, 24576L, 1536L, 96L);            // B'[(a,e),(Y,U)]
  gnn(B2, B3, Sb, 256, 256, CHI*CHI);                       // S[X,V,Y,U]
  k_buildK<<<4, 256, 0, stream>>>(Asym, K6);
  k_Y1<<<4, 256, 0, stream>>>(K6, Sb, Y1);
  k_W16<<<1, 16, 0, stream>>>(K6, Y1, W16);
  k_final<<<1, 1, 0, stream>>>(W16, Hin, Ox, Oy, Oz, (float*)d_out);
}

// Round 3
// 598696.045 us; speedup vs baseline: 1.9431x; 1.9431x over previous
//
#include <hip/hip_runtime.h>
#include <math.h>

#define D2T   16
#define CHI   96
#define NITER 12
#define KSUB  128
#define JSWMAX 12
#define NBRED 128

// ---------------- tiny builders ----------------
__global__ void k_symA(const float* __restrict__ A1, float* __restrict__ As) {
  int i = blockIdx.x * blockDim.x + threadIdx.x;
  if (i >= 128) return;
  int w = i % 4, x = (i / 4) % 4, u = (i / 16) % 4, p = i / 64;
#define AT(pp,aa,bb,cc) A1[(((pp)*4+(aa))*4+(bb))*4+(cc)]
  As[i] = AT(p,u,x,w) + AT(p,u,w,x) + AT(p,x,w,u) + AT(p,w,x,u) + AT(p,w,u,x) + AT(p,x,u,w);
#undef AT
}

__global__ void k_buildT(const float* __restrict__ As, float* __restrict__ T) {
  int i = blockIdx.x * blockDim.x + threadIdx.x;
  if (i >= 4096) return;
  int Wf = i % 16, Xf = (i / 16) % 16, Uf = i / 256;
  int u = Uf >> 2, a = Uf & 3, x = Xf >> 2, b = Xf & 3, w = Wf >> 2, c = Wf & 3;
  float s = 0.f;
  for (int p = 0; p < 2; ++p)
    s += As[((p*4+u)*4+x)*4+w] * As[((p*4+a)*4+b)*4+c];
  T[i] = s;
}

__global__ void k_buildM(const float* __restrict__ T, float* __restrict__ M) {
  int i = blockIdx.x * blockDim.x + threadIdx.x;
  if (i >= 65536) return;
  int y = i % 16, x = (i / 16) % 16, v = (i / 256) % 16, u = i / 4096;
  const float* Tu = T + (u*16 + x)*16;
  const float* Tv = T + (v*16 + y)*16;
  float s = 0.f;
  for (int w = 0; w < 16; ++w) s += Tu[w]*Tv[w];
  M[i] = s;
}

__global__ void k_initC(const float* __restrict__ M, float* __restrict__ C) {
  int i = blockIdx.x * blockDim.x + threadIdx.x;
  if (i >= 256) return;
  int v = i / 16, y = i % 16;
  float s = 0.f;
  for (int u = 0; u < 16; ++u)
    for (int x = 0; x < 16; ++x)
      s += M[((u*16+v)*16+x)*16+y];
  C[v*16+y] = s;
}

__global__ void k_initE(const float* __restrict__ M, float* __restrict__ E) {
  int i = blockIdx.x * blockDim.x + threadIdx.x;
  if (i >= 4096) return;
  int v = i % 16, y = (i / 16) % 16, u = i / 256;
  float s = 0.f;
  for (int x = 0; x < 16; ++x) s += M[((u*16+v)*16+x)*16+y];
  E[(u*16+y)*16+v] = s;   // E[u][y][v], chic=16
}

// ---------------- generic helpers ----------------
__global__ void k_perm4(const float* __restrict__ src, float* __restrict__ dst,
                        int d0, int d1, int d2, int d3,
                        long s0, long s1, long s2, long s3) {
  long n = (long)d0 * d1 * d2 * d3;
  for (long i = blockIdx.x * (long)blockDim.x + threadIdx.x; i < n;
       i += (long)gridDim.x * blockDim.x) {
    int i3 = (int)(i % d3); long t = i / d3;
    int i2 = (int)(t % d2); t /= d2;
    int i1 = (int)(t % d1); int i0 = (int)(t / d1);
    dst[i] = src[i0*s0 + i1*s1 + i2*s2 + i3*s3];
  }
}

__global__ void k_sym2d(float* __restrict__ A, int n) {
  long nn = (long)n * n;
  for (long i = blockIdx.x * (long)blockDim.x + threadIdx.x; i < nn;
       i += (long)gridDim.x * blockDim.x) {
    int r = (int)(i / n), c = (int)(i % n);
    if (r <= c) {
      float v = 0.5f * (A[(long)r*n + c] + A[(long)c*n + r]);
      A[(long)r*n + c] = v; A[(long)c*n + r] = v;
    }
  }
}

__global__ void k_symE(float* __restrict__ E, int chi) {
  long n = (long)chi * 16 * chi;
  for (long i = blockIdx.x * (long)blockDim.x + threadIdx.x; i < n;
       i += (long)gridDim.x * blockDim.x) {
    int b = (int)(i % chi); long t = i / chi;
    int y = (int)(t % 16); int a = (int)(t / 16);
    if (a <= b) {
      long ia = ((long)a*16 + y)*chi + b, ib = ((long)b*16 + y)*chi + a;
      float v = 0.5f * (E[ia] + E[ib]);
      E[ia] = v; E[ib] = v;
    }
  }
}

__global__ void k_sumsq(const float* __restrict__ a, long n, float* __restrict__ partial) {
  __shared__ float red[256];
  float s = 0.f;
  for (long i = blockIdx.x * 256L + threadIdx.x; i < n; i += (long)gridDim.x * 256L) {
    float v = a[i]; s += v*v;
  }
  red[threadIdx.x] = s; __syncthreads();
  for (int o = 128; o; o >>= 1) { if ((int)threadIdx.x < o) red[threadIdx.x] += red[threadIdx.x + o]; __syncthreads(); }
  if (threadIdx.x == 0) partial[blockIdx.x] = red[0];
}

__global__ void k_rsqrt_of_sum(const float* __restrict__ partial, int nb, float* __restrict__ out) {
  __shared__ float red[256];
  float s = 0.f;
  for (int i = threadIdx.x; i < nb; i += 256) s += partial[i];
  red[threadIdx.x] = s; __syncthreads();
  for (int o = 128; o; o >>= 1) { if ((int)threadIdx.x < o) red[threadIdx.x] += red[threadIdx.x + o]; __syncthreads(); }
  if (threadIdx.x == 0) out[0] = rsqrtf(red[0]);
}

__global__ void k_scale(float* __restrict__ a, long n, const float* __restrict__ sc) {
  float f = sc[0];
  for (long i = blockIdx.x * (long)blockDim.x + threadIdx.x; i < n;
       i += (long)gridDim.x * blockDim.x) a[i] *= f;
}

// ---------------- GEMMs (fp32, 64x64 tile, 256 thr, 4x4/thr) ----------------
__global__ __launch_bounds__(256) void k_gemm_nn(const float* __restrict__ A, const float* __restrict__ B,
                                                 float* __restrict__ C, int M, int N, int K) {
  __shared__ float As[16][68];
  __shared__ float Bs[16][68];
  int tid = threadIdx.x, tx = tid % 16, ty = tid / 16;
  int row0 = blockIdx.y*64, col0 = blockIdx.x*64;
  float acc[4][4] = {};
  for (int k0 = 0; k0 < K; k0 += 16) {
    for (int i = tid; i < 16*64; i += 256) {
      int c = i % 16, r = i / 16;
      float v = 0.f;
      if (row0 + r < M && k0 + c < K) v = A[(long)(row0+r)*K + k0 + c];
      As[c][r] = v;
    }
    for (int i = tid; i < 16*64; i += 256) {
      int c = i % 64, r = i / 64;
      float v = 0.f;
      if (k0 + r < K && col0 + c < N) v = B[(long)(k0+r)*N + col0 + c];
      Bs[r][c] = v;
    }
    __syncthreads();
    for (int kk = 0; kk < 16; ++kk) {
      float av[4], bv[4];
#pragma unroll
      for (int ii = 0; ii < 4; ++ii) av[ii] = As[kk][ty*4+ii];
#pragma unroll
      for (int jj = 0; jj < 4; ++jj) bv[jj] = Bs[kk][tx*4+jj];
#pragma unroll
      for (int ii = 0; ii < 4; ++ii)
#pragma unroll
        for (int jj = 0; jj < 4; ++jj) acc[ii][jj] += av[ii]*bv[jj];
    }
    __syncthreads();
  }
  for (int ii = 0; ii < 4; ++ii) {
    int r = row0 + ty*4 + ii;
    if (r >= M) continue;
    for (int jj = 0; jj < 4; ++jj) {
      int c = col0 + tx*4 + jj;
      if (c < N) C[(long)r*N + c] = acc[ii][jj];
    }
  }
}

// C = A^T B (sub=0) or C -= A^T B (sub=1); A is (K x M) row-major, B is (K x N) row-major
__global__ __launch_bounds__(256) void k_gemm_tn(const float* __restrict__ A, const float* __restrict__ B,
                                                 float* __restrict__ C, int M, int N, int K, int sub) {
  __shared__ float As[16][68];
  __shared__ float Bs[16][68];
  int tid = threadIdx.x, tx = tid % 16, ty = tid / 16;
  int row0 = blockIdx.y*64, col0 = blockIdx.x*64;
  float acc[4][4] = {};
  for (int k0 = 0; k0 < K; k0 += 16) {
    for (int i = tid; i < 16*64; i += 256) {
      int r = i % 64, kk = i / 64;
      float v = 0.f;
      if (k0 + kk < K && row0 + r < M) v = A[(long)(k0+kk)*M + row0 + r];
      As[kk][r] = v;
    }
    for (int i = tid; i < 16*64; i += 256) {
      int c = i % 64, kk = i / 64;
      float v = 0.f;
      if (k0 + kk < K && col0 + c < N) v = B[(long)(k0+kk)*N + col0 + c];
      Bs[kk][c] = v;
    }
    __syncthreads();
    for (int kk = 0; kk < 16; ++kk) {
      float av[4], bv[4];
#pragma unroll
      for (int ii = 0; ii < 4; ++ii) av[ii] = As[kk][ty*4+ii];
#pragma unroll
      for (int jj = 0; jj < 4; ++jj) bv[jj] = Bs[kk][tx*4+jj];
#pragma unroll
      for (int ii = 0; ii < 4; ++ii)
#pragma unroll
        for (int jj = 0; jj < 4; ++jj) acc[ii][jj] += av[ii]*bv[jj];
    }
    __syncthreads();
  }
  for (int ii = 0; ii < 4; ++ii) {
    int r = row0 + ty*4 + ii;
    if (r >= M) continue;
    for (int jj = 0; jj < 4; ++jj) {
      int c = col0 + tx*4 + jj;
      if (c < N) {
        if (sub) C[(long)r*N + c] -= acc[ii][jj];
        else     C[(long)r*N + c]  = acc[ii][jj];
      }
    }
  }
}

// C = A B^T ; A is (M x K), B is (N x K) row-major
__global__ __launch_bounds__(256) void k_gemm_nt(const float* __restrict__ A, const float* __restrict__ B,
                                                 float* __restrict__ C, int M, int N, int K) {
  __shared__ float As[16][68];
  __shared__ float Bs[16][68];
  int tid = threadIdx.x, tx = tid % 16, ty = tid / 16;
  int row0 = blockIdx.y*64, col0 = blockIdx.x*64;
  float acc[4][4] = {};
  for (int k0 = 0; k0 < K; k0 += 16) {
    for (int i = tid; i < 16*64; i += 256) {
      int kk = i % 16, r = i / 16;
      float v = 0.f;
      if (row0 + r < M && k0 + kk < K) v = A[(long)(row0+r)*K + k0 + kk];
      As[kk][r] = v;
    }
    for (int i = tid; i < 16*64; i += 256) {
      int kk = i % 16, c = i / 16;
      float v = 0.f;
      if (col0 + c < N && k0 + kk < K) v = B[(long)(col0+c)*K + k0 + kk];
      Bs[kk][c] = v;
    }
    __syncthreads();
    for (int kk = 0; kk < 16; ++kk) {
      float av[4], bv[4];
#pragma unroll
      for (int ii = 0; ii < 4; ++ii) av[ii] = As[kk][ty*4+ii];
#pragma unroll
      for (int jj = 0; jj < 4; ++jj) bv[jj] = Bs[kk][tx*4+jj];
#pragma unroll
      for (int ii = 0; ii < 4; ++ii)
#pragma unroll
        for (int jj = 0; jj < 4; ++jj) acc[ii][jj] += av[ii]*bv[jj];
    }
    __syncthreads();
  }
  for (int ii = 0; ii < 4; ++ii) {
    int r = row0 + ty*4 + ii;
    if (r >= M) continue;
    for (int jj = 0; jj < 4; ++jj) {
      int c = col0 + tx*4 + jj;
      if (c < N) C[(long)r*N + c] = acc[ii][jj];
    }
  }
}

// ---------------- subspace iteration pieces ----------------
__global__ void k_xinit(float* __restrict__ X, int n, unsigned seed) {
  int i = blockIdx.x * blockDim.x + threadIdx.x;
  if (i >= n) return;
  unsigned x = (unsigned)i * 2654435761u + seed;
  x ^= x >> 16; x *= 2246822519u; x ^= x >> 13; x *= 3266489917u; x ^= x >> 16;
  X[i] = (float)x * (1.0f/4294967296.0f) - 0.5f;
}

// Orthonormalize the 32 rows (length Nm) of P in place via CholQR, two internal passes.
// Clamped (rank-deficient) pivots ZERO their row in the solve — no inf/NaN amplification
// (round-2 bug: clamped pivot 1e-15 + huge off-diag L -> overflow in the triangular solve).
__global__ __launch_bounds__(1024) void k_cholqr2(float* __restrict__ P, int Nm) {
  __shared__ float G[32][33];
  __shared__ float L[32][33];
  __shared__ int clampf[32];
  int tid = threadIdx.x, wave = tid >> 6, lane = tid & 63;
  for (int pass = 0; pass < 2; ++pass) {
    // G = P P^T  (528 upper-tri pairs across 16 waves)
    for (int pr = wave; pr < 528; pr += 16) {
      int i = 0, r = pr;
      while (r >= 32 - i) { r -= 32 - i; ++i; }
      int j = i + r;
      const float* Pi = P + (long)i * Nm;
      const float* Pj = P + (long)j * Nm;
      float d = 0.f;
      for (int c = lane; c < Nm; c += 64) d += Pi[c] * Pj[c];
      for (int o = 32; o; o >>= 1) d += __shfl_down(d, o);
      if (lane == 0) { G[i][j] = d; G[j][i] = d; }
    }
    __syncthreads();
    if (tid == 0) {
      float tr = 0.f;
      for (int i = 0; i < 32; ++i) tr += G[i][i];
      float dmin = tr * (1e-10f / 32.f) + 1e-30f;
      for (int k = 0; k < 32; ++k) {
        float d = G[k][k];
        for (int j = 0; j < k; ++j) d -= L[k][j] * L[k][j];
        int bad = (d < dmin) ? 1 : 0;
        clampf[k] = bad;
        if (bad) d = dmin;
        float lkk = sqrtf(d);
        L[k][k] = lkk;
        float inv = 1.f / lkk;
        for (int i = k + 1; i < 32; ++i) {
          if (bad) { L[i][k] = 0.f; continue; }   // decouple dead direction
          float s = G[i][k];
          for (int j = 0; j < k; ++j) s -= L[i][j] * L[k][j];
          L[i][k] = s * inv;
        }
      }
    }
    __syncthreads();
    // P <- L^{-1} P, independent per column; clamped rows are zeroed.
    for (int c = tid; c < Nm; c += 1024) {
      float v[32];
#pragma unroll
      for (int i = 0; i < 32; ++i) v[i] = P[(long)i * Nm + c];
      for (int i = 0; i < 32; ++i) {
        float s = v[i];
        for (int j = 0; j < i; ++j) s -= L[i][j] * v[j];
        v[i] = clampf[i] ? 0.f : (s / L[i][i]);
      }
#pragma unroll
      for (int i = 0; i < 32; ++i) P[(long)i * Nm + c] = v[i];
    }
    __syncthreads();
  }
}

// Cyclic Jacobi eigensolver for symmetric 128x128, LDS-resident, early-exit on convergence.
__global__ __launch_bounds__(1024) void k_jacobi(const float* __restrict__ Bin, float* __restrict__ Vout,
                                                 float* __restrict__ wout, int maxsweeps) {
  const int n = KSUB;
  __shared__ float Bs[KSUB*KSUB];
  __shared__ float Vs[KSUB*KSUB];
  __shared__ float cS[64], sS[64];
  __shared__ int pS[64], qS[64];
  __shared__ float redA[16], redB[16];
  __shared__ int done;
  int tid = threadIdx.x, wave = tid >> 6, lane = tid & 63;
  for (int i = tid; i < n*n; i += 1024) { Bs[i] = Bin[i]; Vs[i] = ((i / n) == (i % n)) ? 1.f : 0.f; }
  if (tid == 0) done = 0;
  __syncthreads();
  for (int sw = 0; sw < maxsweeps; ++sw) {
    for (int r = 0; r < n-1; ++r) {
      if (tid < 64) {
        int k = tid, a, b;
        if (k == 0) { a = n-1; b = r % (n-1); }
        else { a = (r + k) % (n-1); b = (r - k + (n-1)) % (n-1); }
        int p = a < b ? a : b, q = a < b ? b : a;
        float bpp = Bs[p*n+p], bqq = Bs[q*n+q], bpq = Bs[p*n+q];
        float c = 1.f, s = 0.f;
        if (bpq != 0.f) {
          float tau = (bqq - bpp) / (2.f*bpq);
          float t = (tau >= 0.f ? 1.f : -1.f) / (fabsf(tau) + sqrtf(1.f + tau*tau));
          c = rsqrtf(1.f + t*t); s = t*c;
        }
        pS[k] = p; qS[k] = q; cS[k] = c; sS[k] = s;
      }
      __syncthreads();
      for (int t = tid; t < 64*64; t += 1024) {
        int k1 = t >> 6, k2 = t & 63;
        int p1 = pS[k1], q1 = qS[k1]; float c1 = cS[k1], s1 = sS[k1];
        int p2 = pS[k2], q2 = qS[k2]; float c2 = cS[k2], s2 = sS[k2];
        float a = Bs[p1*n+p2], b = Bs[p1*n+q2], d = Bs[q1*n+p2], e = Bs[q1*n+q2];
        float a1 = c1*a - s1*d, b1 = c1*b - s1*e;
        float d1 = s1*a + c1*d, e1 = s1*b + c1*e;
        Bs[p1*n+p2] = c2*a1 - s2*b1; Bs[p1*n+q2] = s2*a1 + c2*b1;
        Bs[q1*n+p2] = c2*d1 - s2*e1; Bs[q1*n+q2] = s2*d1 + c2*e1;
      }
      for (int t = tid; t < 64*n; t += 1024) {
        int k = t >> 7, i = t & (n-1);
        int p = pS[k], q = qS[k]; float c = cS[k], s = sS[k];
        float vp = Vs[i*n+p], vq = Vs[i*n+q];
        Vs[i*n+p] = c*vp - s*vq; Vs[i*n+q] = s*vp + c*vq;
      }
      __syncthreads();
    }
    // convergence check: off-diagonal mass vs diagonal mass
    float offs = 0.f, dias = 0.f;
    for (int i = tid; i < n*n; i += 1024) {
      float v = Bs[i];
      if ((i / n) == (i % n)) dias += v*v; else offs += v*v;
    }
    for (int o = 32; o; o >>= 1) { offs += __shfl_down(offs, o); dias += __shfl_down(dias, o); }
    if (lane == 0) { redA[wave] = offs; redB[wave] = dias; }
    __syncthreads();
    if (tid == 0) {
      float oa = 0.f, db = 0.f;
      for (int wv = 0; wv < 16; ++wv) { oa += redA[wv]; db += redB[wv]; }
      done = (oa <= 3e-13f * db + 1e-30f) ? 1 : 0;
    }
    __syncthreads();
    if (done) break;
  }
  for (int i = tid; i < n; i += 1024) wout[i] = Bs[i*n+i];
  for (int i = tid; i < n*n; i += 1024) Vout[i] = Vs[i];
}

// Full |w|-sort: idx[0..n) sorted by descending |w|; ws/wsn cover the top-k
__global__ void k_select(const float* __restrict__ w, int n, int topk,
                         int* __restrict__ idx, float* __restrict__ ws, float* __restrict__ wsn) {
  if (threadIdx.x != 0 || blockIdx.x != 0) return;
  bool used[KSUB];
  for (int i = 0; i < n; ++i) used[i] = false;
  float ss = 0.f;
  for (int t = 0; t < n; ++t) {
    int best = 0; float bv = -1.f;
    for (int i = 0; i < n; ++i) {
      if (used[i]) continue;
      float av = fabsf(w[i]);
      if (av > bv) { bv = av; best = i; }
    }
    used[best] = true;
    idx[t] = best;
    if (t < topk) { ws[t] = w[best]; ss += w[best]*w[best]; }
  }
  wsn[0] = sqrtf(ss);
}

__global__ void k_setC(float* __restrict__ C, const float* __restrict__ ws,
                       const float* __restrict__ wsn, int chin) {
  int i = blockIdx.x * blockDim.x + threadIdx.x;
  if (i >= chin*chin) return;
  int r = i / chin, c = i % chin;
  C[i] = (r == c) ? ws[r] / wsn[0] : 0.f;
}

__global__ void k_gather(const float* __restrict__ V, const int* __restrict__ idx,
                         float* __restrict__ Vs, int n, int topk) {
  int i = blockIdx.x * blockDim.x + threadIdx.x;
  if (i >= n*topk) return;
  int r = i / topk, a = i % topk;
  Vs[i] = V[r*n + idx[a]];
}

// ---------------- observable stage ----------------
__global__ void k_buildK(const float* __restrict__ As, float* __restrict__ K6) {
  int i = blockIdx.x * blockDim.x + threadIdx.x;
  if (i >= 1024) return;
  int y = i & 3, v = (i>>2)&3, x = (i>>4)&3, u = (i>>6)&3, s = (i>>8)&1, p = (i>>9)&1;
  float acc = 0.f;
  for (int w = 0; w < 4; ++w)
    acc += As[((p*4+u)*4+x)*4+w] * As[((s*4+v)*4+y)*4+w];
  K6[i] = acc;
}

__global__ void k_Y1(const float* __restrict__ K6, const float* __restrict__ S, float* __restrict__ Y1) {
  int i = blockIdx.x * blockDim.x + threadIdx.x;
  if (i >= 1024) return;
  int f = i & 3, e = (i>>2)&3, b = (i>>4)&3, a = (i>>6)&3, s = (i>>8)&1, p = (i>>9)&1;
  float acc = 0.f;
  for (int u = 0; u < 4; ++u)
    for (int x = 0; x < 4; ++x)
      for (int v = 0; v < 4; ++v)
        for (int y = 0; y < 4; ++y)
          acc += K6[((((p*2+s)*4+u)*4+x)*4+v)*4+y]
               * S[(((x*4+b)*16 + (v*4+e))*16 + (y*4+f))*16 + (u*4+a)];
  Y1[i] = acc;
}

__global__ void k_W16(const float* __restrict__ K6, const float* __restrict__ Y1, float* __restrict__ W) {
  int i = threadIdx.x;
  if (i >= 16) return;
  int qr = i >> 2, ps = i & 3;
  float acc = 0.f;
  for (int j = 0; j < 256; ++j) acc += K6[qr*256 + j] * Y1[ps*256 + j];
  W[i] = acc;
}

__global__ void k_final(const float* __restrict__ W, const float* __restrict__ H,
                        const float* __restrict__ Ox, const float* __restrict__ Oy,
                        const float* __restrict__ Oz, float* __restrict__ out) {
  if (threadIdx.x != 0 || blockIdx.x != 0) return;
  float Z = 0.f;
  for (int q = 0; q < 2; ++q)
    for (int r = 0; r < 2; ++r) Z += W[((q*2+r)*2+q)*2+r];
  float ln = 0.f;
  for (int i = 0; i < 16; ++i) ln += H[i]*W[i];
  out[0] = ln / Z;
  const float* Os[3] = {Ox, Oy, Oz};
  for (int k = 0; k < 3; ++k) {
    float vA = 0.f, vB = 0.f;
    for (int q = 0; q < 2; ++q)
      for (int p = 0; p < 2; ++p)
        for (int r = 0; r < 2; ++r)
          vA += Os[k][q*2+p] * W[((q*2+r)*2+p)*2+r];
    for (int q = 0; q < 2; ++q)
      for (int r = 0; r < 2; ++r)
        for (int s = 0; s < 2; ++s)
          vB += Os[k][r*2+s] * W[((q*2+r)*2+q)*2+s];
    out[1+k] = 0.5f*(vA+vB)/Z;
  }
}

// ---------------- host ----------------
static inline unsigned nb256(long n) { long b = (n + 255) / 256; return (unsigned)(b < 1 ? 1 : b); }

extern "C" void kernel_launch(void* const* d_in, const int* in_sizes, int n_in,
                              void* d_out, int out_size, void* d_ws, size_t ws_size,
                              hipStream_t stream) {
  const float* A1  = (const float*)d_in[0];
  const float* Hin = (const float*)d_in[1];
  const float* Ox  = (const float*)d_in[2];
  const float* Oy  = (const float*)d_in[3];
  const float* Oz  = (const float*)d_in[4];

  const long SZ_BIG = 1536L*1536L;
  float* p0 = (float*)d_ws;
  float* Asym = p0; p0 += 128;
  float* Tb   = p0; p0 += 4096;
  float* Mb   = p0; p0 += 65536;
  float* Mp   = p0; p0 += 65536;
  float* Mq   = p0; p0 += 65536;
  float* Ca   = p0; p0 += CHI*CHI;
  float* Cb   = p0; p0 += CHI*CHI;
  float* Ea   = p0; p0 += CHI*D2T*CHI;
  float* Eb   = p0; p0 += CHI*D2T*CHI;
  float* CE   = p0; p0 += CHI*D2T*CHI;
  float* E2   = p0; p0 += CHI*D2T*CHI;
  float* Pb   = p0; p0 += (CHI*D2T)*CHI;
  float* Xa   = p0; p0 += KSUB*(CHI*D2T);
  float* Xb   = p0; p0 += KSUB*(CHI*D2T);
  float* Bsm  = p0; p0 += KSUB*KSUB;
  float* Vsm  = p0; p0 += KSUB*KSUB;
  float* Vsrt = p0; p0 += KSUB*KSUB;
  float* Cf   = p0; p0 += KSUB*32;
  float* wv   = p0; p0 += KSUB;
  float* wsv  = p0; p0 += KSUB;
  float* wsn  = p0; p0 += 16;
  float* scal = p0; p0 += 16;
  float* part = p0; p0 += NBRED;
  int*   idx  = (int*)p0; p0 += KSUB;
  float* Vsel = p0; p0 += KSUB*CHI;
  float* K6   = p0; p0 += 1024;
  float* Y1   = p0; p0 += 1024;
  float* W16  = p0; p0 += 16;
  float* tb   = p0; p0 += CHI*D2T*CHI;
  float* ub   = p0; p0 += CHI*D2T*CHI;
  float* Sb   = p0; p0 += 65536;
  float* B1   = p0; p0 += SZ_BIG;
  float* B2   = p0; p0 += SZ_BIG;
  float* B3   = p0; p0 += SZ_BIG;
  if ((size_t)((char*)p0 - (char*)d_ws) > ws_size) return;

  auto normalize = [&](float* a, long n) {
    int nb = (int)((n + 255) / 256); if (nb > NBRED) nb = NBRED;
    k_sumsq<<<nb, 256, 0, stream>>>(a, n, part);
    k_rsqrt_of_sum<<<1, 256, 0, stream>>>(part, nb, scal);
    k_scale<<<nb256(n), 256, 0, stream>>>(a, n, scal);
  };
  auto gnn = [&](const float* A, const float* B, float* C, int M, int N, int K) {
    dim3 g((N+63)/64, (M+63)/64);
    k_gemm_nn<<<g, 256, 0, stream>>>(A, B, C, M, N, K);
  };
  auto gtn = [&](const float* A, const float* B, float* C, int M, int N, int K, int sub = 0) {
    dim3 g((N+63)/64, (M+63)/64);
    k_gemm_tn<<<g, 256, 0, stream>>>(A, B, C, M, N, K, sub);
  };
  auto gnt = [&](const float* A, const float* B, float* C, int M, int N, int K) {
    dim3 g((N+63)/64, (M+63)/64);
    k_gemm_nt<<<g, 256, 0, stream>>>(A, B, C, M, N, K);
  };
  // BCGS2 (panel=32) + intra-panel CholQR2: orthonormalize the 128 rows of Y (128 x Nm)
  auto ORTH = [&](float* Y, int Nm) {
    for (int p = 0; p < 4; ++p) {
      float* panel = Y + (long)p * 32 * Nm;
      if (p > 0) {
        for (int pass = 0; pass < 2; ++pass) {
          gnt(Y, panel, Cf, p*32, 32, Nm);        // Cf = Qprev panel^T
          gtn(Cf, Y, panel, 32, Nm, p*32, 1);     // panel -= Cf^T Qprev
        }
      }
      k_cholqr2<<<1, 1024, 0, stream>>>(panel, Nm);
    }
  };

  // ---- Stage A ----
  k_symA<<<1, 128, 0, stream>>>(A1, Asym);
  k_buildT<<<16, 256, 0, stream>>>(Asym, Tb);
  normalize(Tb, 4096);
  k_buildM<<<256, 256, 0, stream>>>(Tb, Mb);
  normalize(Mb, 65536);
  k_perm4<<<256, 256, 0, stream>>>(Mb, Mp, 16,16,16,16, 16L,4096L,256L,1L);   // Mp[(x,u),(v,y)]
  k_perm4<<<256, 256, 0, stream>>>(Mb, Mq, 16,16,16,16, 4096L,16L,256L,1L);   // Mq[(u,x),(v,y)]
  k_initC<<<1, 256, 0, stream>>>(Mb, Ca);
  k_sym2d<<<1, 256, 0, stream>>>(Ca, 16);
  normalize(Ca, 256);
  k_initE<<<16, 256, 0, stream>>>(Mb, Ea);
  k_symE<<<16, 256, 0, stream>>>(Ea, 16);
  normalize(Ea, 4096);

  // ---- CTMRG iterations ----
  float* Ccur = Ca; float* Calt = Cb;
  float* Ecur = Ea; float* Ealt = Eb;
  float* Xc = Xa; float* Yc = Xb;   // persistent subspace basis (warm-started)
  int chic = 16;
  for (int it = 0; it < NITER; ++it) {
    int Nm = chic * D2T;
    int chin = CHI;
    // Rho build: m[(i,v),(j,y)]
    gnn(Ccur, Ecur, CE, chic, D2T*chic, chic);                                 // CE[a,(x,i)]
    k_perm4<<<nb256((long)chic*chic*16), 256, 0, stream>>>(Ecur, E2,
        chic, chic, 16, 1, 1L, (long)16*chic, (long)chic, 0L);                 // E2[a,(j,u)]
    gtn(CE, E2, B1, 16*chic, 16*chic, chic);                                   // D1[(x,i),(j,u)]
    k_perm4<<<nb256((long)Nm*Nm), 256, 0, stream>>>(B1, B2,
        chic, chic, 16, 16, (long)16*chic, 16L, (long)chic*16*chic, 1L);       // D1p[(i,j),(x,u)]
    gnn(B2, Mp, B1, chic*chic, 256, 256);                                      // Q[(i,j),(v,y)]
    k_perm4<<<nb256((long)Nm*Nm), 256, 0, stream>>>(B1, B2,
        chic, 16, chic, 16, (long)chic*256, 16L, 256L, 1L);                    // m[(i,v),(j,y)]
    k_sym2d<<<nb256((long)Nm*Nm), 256, 0, stream>>>(B2, Nm);
    float* msym = B2;
    // Subspace iteration for top eigenpairs by |lambda| (warm-started for it>=2)
    int nq = (it <= 1) ? 10 : (it == 2) ? 6 : 4;
    if (it <= 1)
      k_xinit<<<nb256((long)KSUB*Nm), 256, 0, stream>>>(Xc, KSUB*Nm, 0x9E3779B9u);
    for (int t = 0; t < nq; ++t) {
      gnn(Xc, msym, Yc, KSUB, Nm, Nm);      // Y = X m  (m symmetric)
      ORTH(Yc, Nm);
      float* tm = Xc; Xc = Yc; Yc = tm;
    }
    gnn(Xc, msym, Yc, KSUB, Nm, Nm);        // Y2 = X m
    gnt(Yc, Xc, Bsm, KSUB, KSUB, Nm);       // B = X m X^T
    k_sym2d<<<nb256((long)KSUB*KSUB), 256, 0, stream>>>(Bsm, KSUB);
    k_jacobi<<<1, 1024, 0, stream>>>(Bsm, Vsm, wv, JSWMAX);
    k_select<<<1, 1, 0, stream>>>(wv, KSUB, chin, idx, wsv, wsn);
    k_setC<<<nb256((long)chin*chin), 256, 0, stream>>>(Calt, wsv, wsn, chin);
    k_gather<<<nb256((long)KSUB*chin), 256, 0, stream>>>(Vsm, idx, Vsel, KSUB, chin);
    gtn(Xc, Vsel, Pb, Nm, chin, KSUB);      // P (Nm x chin) = Ritz vectors
    // Warm start for next iteration: rotate full basis into Ritz order (Nm unchanged for it>=1)
    if (it >= 1 && it < NITER-1) {
      k_gather<<<nb256((long)KSUB*KSUB), 256, 0, stream>>>(Vsm, idx, Vsrt, KSUB, KSUB);
      gtn(Vsrt, Xc, Yc, KSUB, Nm, KSUB);    // Xnew = Vsrt^T Xc
      float* tm = Xc; Xc = Yc; Yc = tm;
    }
    // E update: Enew[a,y,b]
    gtn(Pb, Ecur, B1, D2T*chin, D2T*chic, chic);                               // T1[(u,a),(x,j)]
    k_perm4<<<nb256((long)D2T*chin*D2T*chic), 256, 0, stream>>>(B1, B2,
        chin, chic, 16, 16, (long)16*chic, 1L, (long)chin*16*chic, (long)chic);// T1p[(a,j),(u,x)]
    gnn(B2, Mq, B1, chin*chic, 256, 256);                                      // T2[(a,j),(v,y)]
    k_perm4<<<nb256((long)chin*chic*256), 256, 0, stream>>>(B1, B2,
        chin, 16, chic, 16, (long)chic*256, 1L, 256L, 16L);                    // T2p[(a,y),(j,v)]
    gnn(B2, Pb, Ealt, chin*D2T, chin, chic*D2T);                               // Enew[(a,y),b]
    k_symE<<<nb256((long)chin*16*chin), 256, 0, stream>>>(Ealt, chin);
    normalize(Ealt, (long)chin*16*chin);
    { float* t1 = Ccur; Ccur = Calt; Calt = t1; }
    { float* t1 = Ecur; Ecur = Ealt; Ealt = t1; }
    chic = chin;
  }

  // ---- Environment closure: S_env and observables ----
  gnn(Ccur, Ecur, tb, CHI, D2T*CHI, CHI);                   // t[a,(x,c)]
  gnn(tb, Ccur, ub, CHI*D2T, CHI, CHI);                     // up[(a,x),d]
  gnn(ub, Ecur, B1, CHI*D2T, D2T*CHI, CHI);                 // T1env[(a,x),(v,e)]
  k_perm4<<<nb256(SZ_BIG), 256, 0, stream>>>(B1, B2,
      16, 16, CHI, CHI, 1536L, 96L, 24576L, 1L);            // A'[(X,V),(a,e)]
  k_perm4<<<nb256(SZ_BIG), 256, 0, stream>>>(B1, B3,
      CHI, CHI, 16, 16, 1L, 24576L, 1536L, 96L);            // B'[(a,e),(Y,U)]
  gnn(B2, B3, Sb, 256, 256, CHI*CHI);                       // S[X,V,Y,U]
  k_buildK<<<4, 256, 0, stream>>>(Asym, K6);
  k_Y1<<<4, 256, 0, stream>>>(K6, Sb, Y1);
  k_W16<<<1, 16, 0, stream>>>(K6, Y1, W16);
  k_final<<<1, 1, 0, stream>>>(W16, Hin, Ox, Oy, Oz, (float*)d_out);
}

// Round 4
// 149167.615 us; speedup vs baseline: 7.7989x; 4.0136x over previous
//
#include <hip/hip_runtime.h>
#include <math.h>

#define D2T   16
#define CHI   96
#define NITER 12
#define KSUB  128
#define JSWMAX 12
#define NBRED 128

// ---------------- tiny builders ----------------
__global__ void k_symA(const float* __restrict__ A1, float* __restrict__ As) {
  int i = blockIdx.x * blockDim.x + threadIdx.x;
  if (i >= 128) return;
  int w = i % 4, x = (i / 4) % 4, u = (i / 16) % 4, p = i / 64;
#define AT(pp,aa,bb,cc) A1[(((pp)*4+(aa))*4+(bb))*4+(cc)]
  As[i] = AT(p,u,x,w) + AT(p,u,w,x) + AT(p,x,w,u) + AT(p,w,x,u) + AT(p,w,u,x) + AT(p,x,u,w);
#undef AT
}

__global__ void k_buildT(const float* __restrict__ As, float* __restrict__ T) {
  int i = blockIdx.x * blockDim.x + threadIdx.x;
  if (i >= 4096) return;
  int Wf = i % 16, Xf = (i / 16) % 16, Uf = i / 256;
  int u = Uf >> 2, a = Uf & 3, x = Xf >> 2, b = Xf & 3, w = Wf >> 2, c = Wf & 3;
  float s = 0.f;
  for (int p = 0; p < 2; ++p)
    s += As[((p*4+u)*4+x)*4+w] * As[((p*4+a)*4+b)*4+c];
  T[i] = s;
}

__global__ void k_buildM(const float* __restrict__ T, float* __restrict__ M) {
  int i = blockIdx.x * blockDim.x + threadIdx.x;
  if (i >= 65536) return;
  int y = i % 16, x = (i / 16) % 16, v = (i / 256) % 16, u = i / 4096;
  const float* Tu = T + (u*16 + x)*16;
  const float* Tv = T + (v*16 + y)*16;
  float s = 0.f;
  for (int w = 0; w < 16; ++w) s += Tu[w]*Tv[w];
  M[i] = s;
}

__global__ void k_initC(const float* __restrict__ M, float* __restrict__ C) {
  int i = blockIdx.x * blockDim.x + threadIdx.x;
  if (i >= 256) return;
  int v = i / 16, y = i % 16;
  float s = 0.f;
  for (int u = 0; u < 16; ++u)
    for (int x = 0; x < 16; ++x)
      s += M[((u*16+v)*16+x)*16+y];
  C[v*16+y] = s;
}

__global__ void k_initE(const float* __restrict__ M, float* __restrict__ E) {
  int i = blockIdx.x * blockDim.x + threadIdx.x;
  if (i >= 4096) return;
  int v = i % 16, y = (i / 16) % 16, u = i / 256;
  float s = 0.f;
  for (int x = 0; x < 16; ++x) s += M[((u*16+v)*16+x)*16+y];
  E[(u*16+y)*16+v] = s;   // E[u][y][v], chic=16
}

// ---------------- generic helpers ----------------
__global__ void k_perm4(const float* __restrict__ src, float* __restrict__ dst,
                        int d0, int d1, int d2, int d3,
                        long s0, long s1, long s2, long s3) {
  long n = (long)d0 * d1 * d2 * d3;
  for (long i = blockIdx.x * (long)blockDim.x + threadIdx.x; i < n;
       i += (long)gridDim.x * blockDim.x) {
    int i3 = (int)(i % d3); long t = i / d3;
    int i2 = (int)(t % d2); t /= d2;
    int i1 = (int)(t % d1); int i0 = (int)(t / d1);
    dst[i] = src[i0*s0 + i1*s1 + i2*s2 + i3*s3];
  }
}

__global__ void k_sym2d(float* __restrict__ A, int n) {
  long nn = (long)n * n;
  for (long i = blockIdx.x * (long)blockDim.x + threadIdx.x; i < nn;
       i += (long)gridDim.x * blockDim.x) {
    int r = (int)(i / n), c = (int)(i % n);
    if (r <= c) {
      float v = 0.5f * (A[(long)r*n + c] + A[(long)c*n + r]);
      A[(long)r*n + c] = v; A[(long)c*n + r] = v;
    }
  }
}

__global__ void k_symE(float* __restrict__ E, int chi) {
  long n = (long)chi * 16 * chi;
  for (long i = blockIdx.x * (long)blockDim.x + threadIdx.x; i < n;
       i += (long)gridDim.x * blockDim.x) {
    int b = (int)(i % chi); long t = i / chi;
    int y = (int)(t % 16); int a = (int)(t / 16);
    if (a <= b) {
      long ia = ((long)a*16 + y)*chi + b, ib = ((long)b*16 + y)*chi + a;
      float v = 0.5f * (E[ia] + E[ib]);
      E[ia] = v; E[ib] = v;
    }
  }
}

__global__ void k_sumsq(const float* __restrict__ a, long n, float* __restrict__ partial) {
  __shared__ float red[256];
  float s = 0.f;
  for (long i = blockIdx.x * 256L + threadIdx.x; i < n; i += (long)gridDim.x * 256L) {
    float v = a[i]; s += v*v;
  }
  red[threadIdx.x] = s; __syncthreads();
  for (int o = 128; o; o >>= 1) { if ((int)threadIdx.x < o) red[threadIdx.x] += red[threadIdx.x + o]; __syncthreads(); }
  if (threadIdx.x == 0) partial[blockIdx.x] = red[0];
}

// fused: reduce partials -> rsqrt -> scale slice (each block redundantly reduces; nb<=128)
__global__ void k_scale_sumsq(float* __restrict__ a, long n,
                              const float* __restrict__ partial, int nb) {
  __shared__ float red[256];
  float s = 0.f;
  for (int i = threadIdx.x; i < nb; i += 256) s += partial[i];
  red[threadIdx.x] = s; __syncthreads();
  for (int o = 128; o; o >>= 1) { if ((int)threadIdx.x < o) red[threadIdx.x] += red[threadIdx.x + o]; __syncthreads(); }
  float f = rsqrtf(red[0]);
  for (long i = blockIdx.x * (long)blockDim.x + threadIdx.x; i < n;
       i += (long)gridDim.x * blockDim.x) a[i] *= f;
}

// ---------------- GEMMs (fp32, 64x64 tile, 256 thr, 4x4/thr) ----------------
__global__ __launch_bounds__(256) void k_gemm_nn(const float* __restrict__ A, const float* __restrict__ B,
                                                 float* __restrict__ C, int M, int N, int K) {
  __shared__ float As[16][68];
  __shared__ float Bs[16][68];
  int tid = threadIdx.x, tx = tid % 16, ty = tid / 16;
  int row0 = blockIdx.y*64, col0 = blockIdx.x*64;
  float acc[4][4] = {};
  for (int k0 = 0; k0 < K; k0 += 16) {
    for (int i = tid; i < 16*64; i += 256) {
      int c = i % 16, r = i / 16;
      float v = 0.f;
      if (row0 + r < M && k0 + c < K) v = A[(long)(row0+r)*K + k0 + c];
      As[c][r] = v;
    }
    for (int i = tid; i < 16*64; i += 256) {
      int c = i % 64, r = i / 64;
      float v = 0.f;
      if (k0 + r < K && col0 + c < N) v = B[(long)(k0+r)*N + col0 + c];
      Bs[r][c] = v;
    }
    __syncthreads();
    for (int kk = 0; kk < 16; ++kk) {
      float av[4], bv[4];
#pragma unroll
      for (int ii = 0; ii < 4; ++ii) av[ii] = As[kk][ty*4+ii];
#pragma unroll
      for (int jj = 0; jj < 4; ++jj) bv[jj] = Bs[kk][tx*4+jj];
#pragma unroll
      for (int ii = 0; ii < 4; ++ii)
#pragma unroll
        for (int jj = 0; jj < 4; ++jj) acc[ii][jj] += av[ii]*bv[jj];
    }
    __syncthreads();
  }
  for (int ii = 0; ii < 4; ++ii) {
    int r = row0 + ty*4 + ii;
    if (r >= M) continue;
    for (int jj = 0; jj < 4; ++jj) {
      int c = col0 + tx*4 + jj;
      if (c < N) C[(long)r*N + c] = acc[ii][jj];
    }
  }
}

// C = A^T B (sub=0) or C -= A^T B (sub=1); A is (K x M) row-major, B is (K x N) row-major
__global__ __launch_bounds__(256) void k_gemm_tn(const float* __restrict__ A, const float* __restrict__ B,
                                                 float* __restrict__ C, int M, int N, int K, int sub) {
  __shared__ float As[16][68];
  __shared__ float Bs[16][68];
  int tid = threadIdx.x, tx = tid % 16, ty = tid / 16;
  int row0 = blockIdx.y*64, col0 = blockIdx.x*64;
  float acc[4][4] = {};
  for (int k0 = 0; k0 < K; k0 += 16) {
    for (int i = tid; i < 16*64; i += 256) {
      int r = i % 64, kk = i / 64;
      float v = 0.f;
      if (k0 + kk < K && row0 + r < M) v = A[(long)(k0+kk)*M + row0 + r];
      As[kk][r] = v;
    }
    for (int i = tid; i < 16*64; i += 256) {
      int c = i % 64, kk = i / 64;
      float v = 0.f;
      if (k0 + kk < K && col0 + c < N) v = B[(long)(k0+kk)*N + col0 + c];
      Bs[kk][c] = v;
    }
    __syncthreads();
    for (int kk = 0; kk < 16; ++kk) {
      float av[4], bv[4];
#pragma unroll
      for (int ii = 0; ii < 4; ++ii) av[ii] = As[kk][ty*4+ii];
#pragma unroll
      for (int jj = 0; jj < 4; ++jj) bv[jj] = Bs[kk][tx*4+jj];
#pragma unroll
      for (int ii = 0; ii < 4; ++ii)
#pragma unroll
        for (int jj = 0; jj < 4; ++jj) acc[ii][jj] += av[ii]*bv[jj];
    }
    __syncthreads();
  }
  for (int ii = 0; ii < 4; ++ii) {
    int r = row0 + ty*4 + ii;
    if (r >= M) continue;
    for (int jj = 0; jj < 4; ++jj) {
      int c = col0 + tx*4 + jj;
      if (c < N) {
        if (sub) C[(long)r*N + c] -= acc[ii][jj];
        else     C[(long)r*N + c]  = acc[ii][jj];
      }
    }
  }
}

// C = A B^T ; A is (M x K), B is (N x K) row-major
__global__ __launch_bounds__(256) void k_gemm_nt(const float* __restrict__ A, const float* __restrict__ B,
                                                 float* __restrict__ C, int M, int N, int K) {
  __shared__ float As[16][68];
  __shared__ float Bs[16][68];
  int tid = threadIdx.x, tx = tid % 16, ty = tid / 16;
  int row0 = blockIdx.y*64, col0 = blockIdx.x*64;
  float acc[4][4] = {};
  for (int k0 = 0; k0 < K; k0 += 16) {
    for (int i = tid; i < 16*64; i += 256) {
      int kk = i % 16, r = i / 16;
      float v = 0.f;
      if (row0 + r < M && k0 + kk < K) v = A[(long)(row0+r)*K + k0 + kk];
      As[kk][r] = v;
    }
    for (int i = tid; i < 16*64; i += 256) {
      int kk = i % 16, c = i / 16;
      float v = 0.f;
      if (col0 + c < N && k0 + kk < K) v = B[(long)(col0+c)*K + k0 + kk];
      Bs[kk][c] = v;
    }
    __syncthreads();
    for (int kk = 0; kk < 16; ++kk) {
      float av[4], bv[4];
#pragma unroll
      for (int ii = 0; ii < 4; ++ii) av[ii] = As[kk][ty*4+ii];
#pragma unroll
      for (int jj = 0; jj < 4; ++jj) bv[jj] = Bs[kk][tx*4+jj];
#pragma unroll
      for (int ii = 0; ii < 4; ++ii)
#pragma unroll
        for (int jj = 0; jj < 4; ++jj) acc[ii][jj] += av[ii]*bv[jj];
    }
    __syncthreads();
  }
  for (int ii = 0; ii < 4; ++ii) {
    int r = row0 + ty*4 + ii;
    if (r >= M) continue;
    for (int jj = 0; jj < 4; ++jj) {
      int c = col0 + tx*4 + jj;
      if (c < N) C[(long)r*N + c] = acc[ii][jj];
    }
  }
}

// ---------------- subspace iteration pieces ----------------
__global__ void k_xinit(float* __restrict__ X, int n, unsigned seed) {
  int i = blockIdx.x * blockDim.x + threadIdx.x;
  if (i >= n) return;
  unsigned x = (unsigned)i * 2654435761u + seed;
  x ^= x >> 16; x *= 2246822519u; x ^= x >> 13; x *= 3266489917u; x ^= x >> 16;
  X[i] = (float)x * (1.0f/4294967296.0f) - 0.5f;
}

// Orthonormalize the 32 rows (length Nm) of P in place via CholQR, two internal passes.
// Clamped (rank-deficient) pivots ZERO their row in the solve. Cholesky is wave-0
// wave-synchronous (volatile LDS + wave_barrier), not serial thread-0.
__global__ __launch_bounds__(1024) void k_cholqr2(float* __restrict__ P, int Nm) {
  __shared__ float G[32][33];
  __shared__ int clampf[32];
  __shared__ float dminS;
  int tid = threadIdx.x, wave = tid >> 6, lane = tid & 63;
  for (int pass = 0; pass < 2; ++pass) {
    // G = P P^T  (528 upper-tri pairs across 16 waves)
    for (int pr = wave; pr < 528; pr += 16) {
      int i = 0, r = pr;
      while (r >= 32 - i) { r -= 32 - i; ++i; }
      int j = i + r;
      const float* Pi = P + (long)i * Nm;
      const float* Pj = P + (long)j * Nm;
      float d = 0.f;
      for (int c = lane; c < Nm; c += 64) d += Pi[c] * Pj[c];
      for (int o = 32; o; o >>= 1) d += __shfl_down(d, o);
      if (lane == 0) { G[i][j] = d; G[j][i] = d; }
    }
    __syncthreads();
    if (tid == 0) {
      float tr = 0.f;
      for (int i2 = 0; i2 < 32; ++i2) tr += G[i2][i2];
      dminS = tr * (1e-10f / 32.f) + 1e-30f;
    }
    __syncthreads();
    // in-place Cholesky of G (lower triangle becomes L), wave 0 only
    if (wave == 0) {
      volatile float* Gv = &G[0][0];   // row stride 33
      for (int k = 0; k < 32; ++k) {
        if (lane == 0) {
          float d = Gv[k*33+k];
          int bad = (d < dminS) ? 1 : 0;
          clampf[k] = bad;
          Gv[k*33+k] = sqrtf(bad ? dminS : d);
        }
        __builtin_amdgcn_wave_barrier();
        float lkk = Gv[k*33+k];
        int bad = clampf[k];
        int i2 = k + 1 + lane;
        float lik = 0.f;
        if (i2 < 32) { lik = bad ? 0.f : (Gv[i2*33+k] / lkk); Gv[i2*33+k] = lik; }
        __builtin_amdgcn_wave_barrier();
        for (int j2 = k + 1; j2 < 32; ++j2) {
          float ljk = __shfl(lik, j2 - k - 1);
          if (i2 < 32 && j2 <= i2) Gv[i2*33+j2] -= lik * ljk;
        }
        __builtin_amdgcn_wave_barrier();
      }
    }
    __syncthreads();
    // P <- L^{-1} P per column; clamped rows zeroed (L = lower G)
    for (int c = tid; c < Nm; c += 1024) {
      float v[32];
#pragma unroll
      for (int i2 = 0; i2 < 32; ++i2) v[i2] = P[(long)i2 * Nm + c];
#pragma unroll
      for (int i2 = 0; i2 < 32; ++i2) {
        float s = v[i2];
        for (int j2 = 0; j2 < i2; ++j2) s -= G[i2][j2] * v[j2];
        v[i2] = clampf[i2] ? 0.f : (s / G[i2][i2]);
      }
#pragma unroll
      for (int i2 = 0; i2 < 32; ++i2) P[(long)i2 * Nm + c] = v[i2];
    }
    __syncthreads();
  }
}

// Cyclic Jacobi eigensolver for symmetric 128x128, LDS-resident, early-exit on convergence.
__global__ __launch_bounds__(1024) void k_jacobi(const float* __restrict__ Bin, float* __restrict__ Vout,
                                                 float* __restrict__ wout, int maxsweeps) {
  const int n = KSUB;
  __shared__ float Bs[KSUB*KSUB];
  __shared__ float Vs[KSUB*KSUB];
  __shared__ float cS[64], sS[64];
  __shared__ int pS[64], qS[64];
  __shared__ float redA[16], redB[16];
  __shared__ int done;
  int tid = threadIdx.x, wave = tid >> 6, lane = tid & 63;
  for (int i = tid; i < n*n; i += 1024) { Bs[i] = Bin[i]; Vs[i] = ((i / n) == (i % n)) ? 1.f : 0.f; }
  if (tid == 0) done = 0;
  __syncthreads();
  for (int sw = 0; sw < maxsweeps; ++sw) {
    for (int r = 0; r < n-1; ++r) {
      if (tid < 64) {
        int k = tid, a, b;
        if (k == 0) { a = n-1; b = r % (n-1); }
        else { a = (r + k) % (n-1); b = (r - k + (n-1)) % (n-1); }
        int p = a < b ? a : b, q = a < b ? b : a;
        float bpp = Bs[p*n+p], bqq = Bs[q*n+q], bpq = Bs[p*n+q];
        float c = 1.f, s = 0.f;
        if (bpq != 0.f) {
          float tau = (bqq - bpp) / (2.f*bpq);
          float t = (tau >= 0.f ? 1.f : -1.f) / (fabsf(tau) + sqrtf(1.f + tau*tau));
          c = rsqrtf(1.f + t*t); s = t*c;
        }
        pS[k] = p; qS[k] = q; cS[k] = c; sS[k] = s;
      }
      __syncthreads();
      for (int t = tid; t < 64*64; t += 1024) {
        int k1 = t >> 6, k2 = t & 63;
        int p1 = pS[k1], q1 = qS[k1]; float c1 = cS[k1], s1 = sS[k1];
        int p2 = pS[k2], q2 = qS[k2]; float c2 = cS[k2], s2 = sS[k2];
        float a = Bs[p1*n+p2], b = Bs[p1*n+q2], d = Bs[q1*n+p2], e = Bs[q1*n+q2];
        float a1 = c1*a - s1*d, b1 = c1*b - s1*e;
        float d1 = s1*a + c1*d, e1 = s1*b + c1*e;
        Bs[p1*n+p2] = c2*a1 - s2*b1; Bs[p1*n+q2] = s2*a1 + c2*b1;
        Bs[q1*n+p2] = c2*d1 - s2*e1; Bs[q1*n+q2] = s2*d1 + c2*e1;
      }
      for (int t = tid; t < 64*n; t += 1024) {
        int k = t >> 7, i = t & (n-1);
        int p = pS[k], q = qS[k]; float c = cS[k], s = sS[k];
        float vp = Vs[i*n+p], vq = Vs[i*n+q];
        Vs[i*n+p] = c*vp - s*vq; Vs[i*n+q] = s*vp + c*vq;
      }
      __syncthreads();
    }
    // convergence check: off-diagonal mass vs diagonal mass (relative, fp32-achievable)
    float offs = 0.f, dias = 0.f;
    for (int i = tid; i < n*n; i += 1024) {
      float v = Bs[i];
      if ((i / n) == (i % n)) dias += v*v; else offs += v*v;
    }
    for (int o = 32; o; o >>= 1) { offs += __shfl_down(offs, o); dias += __shfl_down(dias, o); }
    if (lane == 0) { redA[wave] = offs; redB[wave] = dias; }
    __syncthreads();
    if (tid == 0) {
      float oa = 0.f, db = 0.f;
      for (int wv = 0; wv < 16; ++wv) { oa += redA[wv]; db += redB[wv]; }
      done = (oa <= 1e-10f * db + 1e-30f) ? 1 : 0;
    }
    __syncthreads();
    if (done) break;
  }
  for (int i = tid; i < n; i += 1024) wout[i] = Bs[i*n+i];
  for (int i = tid; i < n*n; i += 1024) Vout[i] = Vs[i];
}

// Wave-parallel |w| selection sort: idx[0..n) desc by |w|; ws/wsn over top-k. One wave, n=128.
__global__ void k_select(const float* __restrict__ w, int n, int topk,
                         int* __restrict__ idx, float* __restrict__ ws, float* __restrict__ wsn) {
  int lane = threadIdx.x;   // 64 threads
  float v0 = w[lane], v1 = w[lane + 64];
  float a0 = fabsf(v0), a1 = fabsf(v1);
  float ss = 0.f;
  for (int t = 0; t < n; ++t) {
    float b, bv; int bi;
    if (a0 >= a1) { b = a0; bi = lane; bv = v0; }
    else          { b = a1; bi = lane + 64; bv = v1; }
    for (int o = 32; o; o >>= 1) {
      float ob = __shfl_down(b, o);
      int   oi = __shfl_down(bi, o);
      float ov = __shfl_down(bv, o);
      if (ob > b) { b = ob; bi = oi; bv = ov; }
    }
    bi = __shfl(bi, 0); bv = __shfl(bv, 0);
    if (lane == 0) {
      idx[t] = bi;
      if (t < topk) { ws[t] = bv; ss += bv * bv; }
    }
    if (bi == lane) a0 = -1.f;
    if (bi == lane + 64) a1 = -1.f;
  }
  if (lane == 0) wsn[0] = sqrtf(ss);
}

__global__ void k_setC(float* __restrict__ C, const float* __restrict__ ws,
                       const float* __restrict__ wsn, int chin) {
  int i = blockIdx.x * blockDim.x + threadIdx.x;
  if (i >= chin*chin) return;
  int r = i / chin, c = i % chin;
  C[i] = (r == c) ? ws[r] / wsn[0] : 0.f;
}

__global__ void k_gather(const float* __restrict__ V, const int* __restrict__ idx,
                         float* __restrict__ Vs, int n, int topk) {
  int i = blockIdx.x * blockDim.x + threadIdx.x;
  if (i >= n*topk) return;
  int r = i / topk, a = i % topk;
  Vs[i] = V[r*n + idx[a]];
}

// ---------------- observable stage ----------------
__global__ void k_buildK(const float* __restrict__ As, float* __restrict__ K6) {
  int i = blockIdx.x * blockDim.x + threadIdx.x;
  if (i >= 1024) return;
  int y = i & 3, v = (i>>2)&3, x = (i>>4)&3, u = (i>>6)&3, s = (i>>8)&1, p = (i>>9)&1;
  float acc = 0.f;
  for (int w = 0; w < 4; ++w)
    acc += As[((p*4+u)*4+x)*4+w] * As[((s*4+v)*4+y)*4+w];
  K6[i] = acc;
}

__global__ void k_Y1(const float* __restrict__ K6, const float* __restrict__ S, float* __restrict__ Y1) {
  int i = blockIdx.x * blockDim.x + threadIdx.x;
  if (i >= 1024) return;
  int f = i & 3, e = (i>>2)&3, b = (i>>4)&3, a = (i>>6)&3, s = (i>>8)&1, p = (i>>9)&1;
  float acc = 0.f;
  for (int u = 0; u < 4; ++u)
    for (int x = 0; x < 4; ++x)
      for (int v = 0; v < 4; ++v)
        for (int y = 0; y < 4; ++y)
          acc += K6[((((p*2+s)*4+u)*4+x)*4+v)*4+y]
               * S[(((x*4+b)*16 + (v*4+e))*16 + (y*4+f))*16 + (u*4+a)];
  Y1[i] = acc;
}

__global__ void k_W16(const float* __restrict__ K6, const float* __restrict__ Y1, float* __restrict__ W) {
  int i = threadIdx.x;
  if (i >= 16) return;
  int qr = i >> 2, ps = i & 3;
  float acc = 0.f;
  for (int j = 0; j < 256; ++j) acc += K6[qr*256 + j] * Y1[ps*256 + j];
  W[i] = acc;
}

__global__ void k_final(const float* __restrict__ W, const float* __restrict__ H,
                        const float* __restrict__ Ox, const float* __restrict__ Oy,
                        const float* __restrict__ Oz, float* __restrict__ out) {
  if (threadIdx.x != 0 || blockIdx.x != 0) return;
  float Z = 0.f;
  for (int q = 0; q < 2; ++q)
    for (int r = 0; r < 2; ++r) Z += W[((q*2+r)*2+q)*2+r];
  float ln = 0.f;
  for (int i = 0; i < 16; ++i) ln += H[i]*W[i];
  out[0] = ln / Z;
  const float* Os[3] = {Ox, Oy, Oz};
  for (int k = 0; k < 3; ++k) {
    float vA = 0.f, vB = 0.f;
    for (int q = 0; q < 2; ++q)
      for (int p = 0; p < 2; ++p)
        for (int r = 0; r < 2; ++r)
          vA += Os[k][q*2+p] * W[((q*2+r)*2+p)*2+r];
    for (int q = 0; q < 2; ++q)
      for (int r = 0; r < 2; ++r)
        for (int s = 0; s < 2; ++s)
          vB += Os[k][r*2+s] * W[((q*2+r)*2+q)*2+s];
    out[1+k] = 0.5f*(vA+vB)/Z;
  }
}

// ---------------- host ----------------
static inline unsigned nb256(long n) { long b = (n + 255) / 256; return (unsigned)(b < 1 ? 1 : b); }

extern "C" void kernel_launch(void* const* d_in, const int* in_sizes, int n_in,
                              void* d_out, int out_size, void* d_ws, size_t ws_size,
                              hipStream_t stream) {
  const float* A1  = (const float*)d_in[0];
  const float* Hin = (const float*)d_in[1];
  const float* Ox  = (const float*)d_in[2];
  const float* Oy  = (const float*)d_in[3];
  const float* Oz  = (const float*)d_in[4];

  const long SZ_BIG = 1536L*1536L;
  float* p0 = (float*)d_ws;
  float* Asym = p0; p0 += 128;
  float* Tb   = p0; p0 += 4096;
  float* Mb   = p0; p0 += 65536;
  float* Mp   = p0; p0 += 65536;
  float* Mq   = p0; p0 += 65536;
  float* Ca   = p0; p0 += CHI*CHI;
  float* Cb   = p0; p0 += CHI*CHI;
  float* Ea   = p0; p0 += CHI*D2T*CHI;
  float* Eb   = p0; p0 += CHI*D2T*CHI;
  float* CE   = p0; p0 += CHI*D2T*CHI;
  float* E2   = p0; p0 += CHI*D2T*CHI;
  float* Pb   = p0; p0 += (CHI*D2T)*CHI;
  float* Xa   = p0; p0 += KSUB*(CHI*D2T);
  float* Xb   = p0; p0 += KSUB*(CHI*D2T);
  float* Bsm  = p0; p0 += KSUB*KSUB;
  float* Vsm  = p0; p0 += KSUB*KSUB;
  float* Vsrt = p0; p0 += KSUB*KSUB;
  float* Cf   = p0; p0 += KSUB*32;
  float* wv   = p0; p0 += KSUB;
  float* wsv  = p0; p0 += KSUB;
  float* wsn  = p0; p0 += 16;
  float* part = p0; p0 += NBRED;
  int*   idx  = (int*)p0; p0 += KSUB;
  float* Vsel = p0; p0 += KSUB*CHI;
  float* K6   = p0; p0 += 1024;
  float* Y1   = p0; p0 += 1024;
  float* W16  = p0; p0 += 16;
  float* tb   = p0; p0 += CHI*D2T*CHI;
  float* ub   = p0; p0 += CHI*D2T*CHI;
  float* Sb   = p0; p0 += 65536;
  float* B1   = p0; p0 += SZ_BIG;
  float* B2   = p0; p0 += SZ_BIG;
  float* B3   = p0; p0 += SZ_BIG;
  if ((size_t)((char*)p0 - (char*)d_ws) > ws_size) return;

  auto normalize = [&](float* a, long n) {
    int nb = (int)((n + 255) / 256); if (nb > NBRED) nb = NBRED;
    k_sumsq<<<nb, 256, 0, stream>>>(a, n, part);
    k_scale_sumsq<<<nb256(n), 256, 0, stream>>>(a, n, part, nb);
  };
  auto gnn = [&](const float* A, const float* B, float* C, int M, int N, int K) {
    dim3 g((N+63)/64, (M+63)/64);
    k_gemm_nn<<<g, 256, 0, stream>>>(A, B, C, M, N, K);
  };
  auto gtn = [&](const float* A, const float* B, float* C, int M, int N, int K, int sub = 0) {
    dim3 g((N+63)/64, (M+63)/64);
    k_gemm_tn<<<g, 256, 0, stream>>>(A, B, C, M, N, K, sub);
  };
  auto gnt = [&](const float* A, const float* B, float* C, int M, int N, int K) {
    dim3 g((N+63)/64, (M+63)/64);
    k_gemm_nt<<<g, 256, 0, stream>>>(A, B, C, M, N, K);
  };
  // BCGS (panel=32, `passes` projection sweeps) + intra-panel CholQR2
  auto ORTH = [&](float* Y, int Nm, int passes) {
    for (int p = 0; p < 4; ++p) {
      float* panel = Y + (long)p * 32 * Nm;
      if (p > 0) {
        for (int ps = 0; ps < passes; ++ps) {
          gnt(Y, panel, Cf, p*32, 32, Nm);        // Cf = Qprev panel^T
          gtn(Cf, Y, panel, 32, Nm, p*32, 1);     // panel -= Cf^T Qprev
        }
      }
      k_cholqr2<<<1, 1024, 0, stream>>>(panel, Nm);
    }
  };

  // ---- Stage A ----
  k_symA<<<1, 128, 0, stream>>>(A1, Asym);
  k_buildT<<<16, 256, 0, stream>>>(Asym, Tb);
  normalize(Tb, 4096);
  k_buildM<<<256, 256, 0, stream>>>(Tb, Mb);
  normalize(Mb, 65536);
  k_perm4<<<256, 256, 0, stream>>>(Mb, Mp, 16,16,16,16, 16L,4096L,256L,1L);   // Mp[(x,u),(v,y)]
  k_perm4<<<256, 256, 0, stream>>>(Mb, Mq, 16,16,16,16, 4096L,16L,256L,1L);   // Mq[(u,x),(v,y)]
  k_initC<<<1, 256, 0, stream>>>(Mb, Ca);
  k_sym2d<<<1, 256, 0, stream>>>(Ca, 16);
  normalize(Ca, 256);
  k_initE<<<16, 256, 0, stream>>>(Mb, Ea);
  k_symE<<<16, 256, 0, stream>>>(Ea, 16);
  normalize(Ea, 4096);

  // ---- CTMRG iterations ----
  const int nqs[NITER] = {8, 8, 4, 3, 3, 2, 2, 2, 2, 2, 2, 2};
  float* Ccur = Ca; float* Calt = Cb;
  float* Ecur = Ea; float* Ealt = Eb;
  float* Xc = Xa; float* Yc = Xb;   // persistent subspace basis (warm-started)
  int chic = 16;
  for (int it = 0; it < NITER; ++it) {
    int Nm = chic * D2T;
    int chin = CHI;
    int passes = (it <= 1) ? 2 : 1;
    // Rho build: m[(i,v),(j,y)]
    gnn(Ccur, Ecur, CE, chic, D2T*chic, chic);                                 // CE[a,(x,i)]
    k_perm4<<<nb256((long)chic*chic*16), 256, 0, stream>>>(Ecur, E2,
        chic, chic, 16, 1, 1L, (long)16*chic, (long)chic, 0L);                 // E2[a,(j,u)]
    gtn(CE, E2, B1, 16*chic, 16*chic, chic);                                   // D1[(x,i),(j,u)]
    k_perm4<<<nb256((long)Nm*Nm), 256, 0, stream>>>(B1, B2,
        chic, chic, 16, 16, (long)16*chic, 16L, (long)chic*16*chic, 1L);       // D1p[(i,j),(x,u)]
    gnn(B2, Mp, B1, chic*chic, 256, 256);                                      // Q[(i,j),(v,y)]
    k_perm4<<<nb256((long)Nm*Nm), 256, 0, stream>>>(B1, B2,
        chic, 16, chic, 16, (long)chic*256, 16L, 256L, 1L);                    // m[(i,v),(j,y)]
    k_sym2d<<<nb256((long)Nm*Nm), 256, 0, stream>>>(B2, Nm);
    float* msym = B2;
    // Subspace iteration for top eigenpairs by |lambda| (warm-started for it>=2)
    int nq = nqs[it];
    if (it <= 1)
      k_xinit<<<nb256((long)KSUB*Nm), 256, 0, stream>>>(Xc, KSUB*Nm, 0x9E3779B9u);
    for (int t = 0; t < nq; ++t) {
      gnn(Xc, msym, Yc, KSUB, Nm, Nm);      // Y = X m  (m symmetric)
      ORTH(Yc, Nm, passes);
      float* tm = Xc; Xc = Yc; Yc = tm;
    }
    gnn(Xc, msym, Yc, KSUB, Nm, Nm);        // Y2 = X m
    gnt(Yc, Xc, Bsm, KSUB, KSUB, Nm);       // B = X m X^T
    k_sym2d<<<nb256((long)KSUB*KSUB), 256, 0, stream>>>(Bsm, KSUB);
    k_jacobi<<<1, 1024, 0, stream>>>(Bsm, Vsm, wv, JSWMAX);
    k_select<<<1, 64, 0, stream>>>(wv, KSUB, chin, idx, wsv, wsn);
    k_setC<<<nb256((long)chin*chin), 256, 0, stream>>>(Calt, wsv, wsn, chin);
    k_gather<<<nb256((long)KSUB*chin), 256, 0, stream>>>(Vsm, idx, Vsel, KSUB, chin);
    gtn(Xc, Vsel, Pb, Nm, chin, KSUB);      // P (Nm x chin) = Ritz vectors
    // Warm start for next iteration: rotate full basis into Ritz order (Nm unchanged for it>=1)
    if (it >= 1 && it < NITER-1) {
      k_gather<<<nb256((long)KSUB*KSUB), 256, 0, stream>>>(Vsm, idx, Vsrt, KSUB, KSUB);
      gtn(Vsrt, Xc, Yc, KSUB, Nm, KSUB);    // Xnew = Vsrt^T Xc
      float* tm = Xc; Xc = Yc; Yc = tm;
    }
    // E update: Enew[a,y,b]
    gtn(Pb, Ecur, B1, D2T*chin, D2T*chic, chic);                               // T1[(u,a),(x,j)]
    k_perm4<<<nb256((long)D2T*chin*D2T*chic), 256, 0, stream>>>(B1, B2,
        chin, chic, 16, 16, (long)16*chic, 1L, (long)chin*16*chic, (long)chic);// T1p[(a,j),(u,x)]
    gnn(B2, Mq, B1, chin*chic, 256, 256);                                      // T2[(a,j),(v,y)]
    k_perm4<<<nb256((long)chin*chic*256), 256, 0, stream>>>(B1, B2,
        chin, 16, chic, 16, (long)chic*256, 1L, 256L, 16L);                    // T2p[(a,y),(j,v)]
    gnn(B2, Pb, Ealt, chin*D2T, chin, chic*D2T);                               // Enew[(a,y),b]
    k_symE<<<nb256((long)chin*16*chin), 256, 0, stream>>>(Ealt, chin);
    normalize(Ealt, (long)chin*16*chin);
    { float* t1 = Ccur; Ccur = Calt; Calt = t1; }
    { float* t1 = Ecur; Ecur = Ealt; Ealt = t1; }
    chic = chin;
  }

  // ---- Environment closure: S_env and observables ----
  gnn(Ccur, Ecur, tb, CHI, D2T*CHI, CHI);                   // t[a,(x,c)]
  gnn(tb, Ccur, ub, CHI*D2T, CHI, CHI);                     // up[(a,x),d]
  gnn(ub, Ecur, B1, CHI*D2T, D2T*CHI, CHI);                 // T1env[(a,x),(v,e)]
  k_perm4<<<nb256(SZ_BIG), 256, 0, stream>>>(B1, B2,
      16, 16, CHI, CHI, 1536L, 96L, 24576L, 1L);            // A'[(X,V),(a,e)]
  k_perm4<<<nb256(SZ_BIG), 256, 0, stream>>>(B1, B3,
      CHI, CHI, 16, 16, 1L, 24576L, 1536L, 96L);            // B'[(a,e),(Y,U)]
  gnn(B2, B3, Sb, 256, 256, CHI*CHI);                       // S[X,V,Y,U]
  k_buildK<<<4, 256, 0, stream>>>(Asym, K6);
  k_Y1<<<4, 256, 0, stream>>>(K6, Sb, Y1);
  k_W16<<<1, 16, 0, stream>>>(K6, Y1, W16);
  k_final<<<1, 1, 0, stream>>>(W16, Hin, Ox, Oy, Oz, (float*)d_out);
}

// Round 5
// 49490.955 us; speedup vs baseline: 23.5061x; 3.0140x over previous
//
#include <hip/hip_runtime.h>
#include <math.h>

#define D2T   16
#define CHI   96
#define NITER 12
#define KSUB  128
#define JSWMAX 12
#define NBRED 128

// ---------------- tiny builders ----------------
__global__ void k_symA(const float* __restrict__ A1, float* __restrict__ As) {
  int i = blockIdx.x * blockDim.x + threadIdx.x;
  if (i >= 128) return;
  int w = i % 4, x = (i / 4) % 4, u = (i / 16) % 4, p = i / 64;
#define AT(pp,aa,bb,cc) A1[(((pp)*4+(aa))*4+(bb))*4+(cc)]
  As[i] = AT(p,u,x,w) + AT(p,u,w,x) + AT(p,x,w,u) + AT(p,w,x,u) + AT(p,w,u,x) + AT(p,x,u,w);
#undef AT
}

__global__ void k_buildT(const float* __restrict__ As, float* __restrict__ T) {
  int i = blockIdx.x * blockDim.x + threadIdx.x;
  if (i >= 4096) return;
  int Wf = i % 16, Xf = (i / 16) % 16, Uf = i / 256;
  int u = Uf >> 2, a = Uf & 3, x = Xf >> 2, b = Xf & 3, w = Wf >> 2, c = Wf & 3;
  float s = 0.f;
  for (int p = 0; p < 2; ++p)
    s += As[((p*4+u)*4+x)*4+w] * As[((p*4+a)*4+b)*4+c];
  T[i] = s;
}

__global__ void k_buildM(const float* __restrict__ T, float* __restrict__ M) {
  int i = blockIdx.x * blockDim.x + threadIdx.x;
  if (i >= 65536) return;
  int y = i % 16, x = (i / 16) % 16, v = (i / 256) % 16, u = i / 4096;
  const float* Tu = T + (u*16 + x)*16;
  const float* Tv = T + (v*16 + y)*16;
  float s = 0.f;
  for (int w = 0; w < 16; ++w) s += Tu[w]*Tv[w];
  M[i] = s;
}

__global__ void k_initC(const float* __restrict__ M, float* __restrict__ C) {
  int i = blockIdx.x * blockDim.x + threadIdx.x;
  if (i >= 256) return;
  int v = i / 16, y = i % 16;
  float s = 0.f;
  for (int u = 0; u < 16; ++u)
    for (int x = 0; x < 16; ++x)
      s += M[((u*16+v)*16+x)*16+y];
  C[v*16+y] = s;
}

__global__ void k_initE(const float* __restrict__ M, float* __restrict__ E) {
  int i = blockIdx.x * blockDim.x + threadIdx.x;
  if (i >= 4096) return;
  int v = i % 16, y = (i / 16) % 16, u = i / 256;
  float s = 0.f;
  for (int x = 0; x < 16; ++x) s += M[((u*16+v)*16+x)*16+y];
  E[(u*16+y)*16+v] = s;   // E[u][y][v], chic=16
}

// ---------------- generic helpers ----------------
__global__ void k_perm4(const float* __restrict__ src, float* __restrict__ dst,
                        int d0, int d1, int d2, int d3,
                        long s0, long s1, long s2, long s3) {
  long n = (long)d0 * d1 * d2 * d3;
  for (long i = blockIdx.x * (long)blockDim.x + threadIdx.x; i < n;
       i += (long)gridDim.x * blockDim.x) {
    int i3 = (int)(i % d3); long t = i / d3;
    int i2 = (int)(t % d2); t /= d2;
    int i1 = (int)(t % d1); int i0 = (int)(t / d1);
    dst[i] = src[i0*s0 + i1*s1 + i2*s2 + i3*s3];
  }
}

__global__ void k_sym2d(float* __restrict__ A, int n) {
  long nn = (long)n * n;
  for (long i = blockIdx.x * (long)blockDim.x + threadIdx.x; i < nn;
       i += (long)gridDim.x * blockDim.x) {
    int r = (int)(i / n), c = (int)(i % n);
    if (r <= c) {
      float v = 0.5f * (A[(long)r*n + c] + A[(long)c*n + r]);
      A[(long)r*n + c] = v; A[(long)c*n + r] = v;
    }
  }
}

__global__ void k_symE(float* __restrict__ E, int chi) {
  long n = (long)chi * 16 * chi;
  for (long i = blockIdx.x * (long)blockDim.x + threadIdx.x; i < n;
       i += (long)gridDim.x * blockDim.x) {
    int b = (int)(i % chi); long t = i / chi;
    int y = (int)(t % 16); int a = (int)(t / 16);
    if (a <= b) {
      long ia = ((long)a*16 + y)*chi + b, ib = ((long)b*16 + y)*chi + a;
      float v = 0.5f * (E[ia] + E[ib]);
      E[ia] = v; E[ib] = v;
    }
  }
}

__global__ void k_sumsq(const float* __restrict__ a, long n, float* __restrict__ partial) {
  __shared__ float red[256];
  float s = 0.f;
  for (long i = blockIdx.x * 256L + threadIdx.x; i < n; i += (long)gridDim.x * 256L) {
    float v = a[i]; s += v*v;
  }
  red[threadIdx.x] = s; __syncthreads();
  for (int o = 128; o; o >>= 1) { if ((int)threadIdx.x < o) red[threadIdx.x] += red[threadIdx.x + o]; __syncthreads(); }
  if (threadIdx.x == 0) partial[blockIdx.x] = red[0];
}

// fused: reduce partials -> rsqrt -> scale slice (each block redundantly reduces; nb<=128)
__global__ void k_scale_sumsq(float* __restrict__ a, long n,
                              const float* __restrict__ partial, int nb) {
  __shared__ float red[256];
  float s = 0.f;
  for (int i = threadIdx.x; i < nb; i += 256) s += partial[i];
  red[threadIdx.x] = s; __syncthreads();
  for (int o = 128; o; o >>= 1) { if ((int)threadIdx.x < o) red[threadIdx.x] += red[threadIdx.x + o]; __syncthreads(); }
  float f = rsqrtf(red[0]);
  for (long i = blockIdx.x * (long)blockDim.x + threadIdx.x; i < n;
       i += (long)gridDim.x * blockDim.x) a[i] *= f;
}

// ---------------- GEMMs (fp32, 64x64 tile, 256 thr, 4x4/thr) ----------------
__global__ __launch_bounds__(256) void k_gemm_nn(const float* __restrict__ A, const float* __restrict__ B,
                                                 float* __restrict__ C, int M, int N, int K) {
  __shared__ float As[16][68];
  __shared__ float Bs[16][68];
  int tid = threadIdx.x, tx = tid % 16, ty = tid / 16;
  int row0 = blockIdx.y*64, col0 = blockIdx.x*64;
  float acc[4][4] = {};
  for (int k0 = 0; k0 < K; k0 += 16) {
    for (int i = tid; i < 16*64; i += 256) {
      int c = i % 16, r = i / 16;
      float v = 0.f;
      if (row0 + r < M && k0 + c < K) v = A[(long)(row0+r)*K + k0 + c];
      As[c][r] = v;
    }
    for (int i = tid; i < 16*64; i += 256) {
      int c = i % 64, r = i / 64;
      float v = 0.f;
      if (k0 + r < K && col0 + c < N) v = B[(long)(k0+r)*N + col0 + c];
      Bs[r][c] = v;
    }
    __syncthreads();
    for (int kk = 0; kk < 16; ++kk) {
      float av[4], bv[4];
#pragma unroll
      for (int ii = 0; ii < 4; ++ii) av[ii] = As[kk][ty*4+ii];
#pragma unroll
      for (int jj = 0; jj < 4; ++jj) bv[jj] = Bs[kk][tx*4+jj];
#pragma unroll
      for (int ii = 0; ii < 4; ++ii)
#pragma unroll
        for (int jj = 0; jj < 4; ++jj) acc[ii][jj] += av[ii]*bv[jj];
    }
    __syncthreads();
  }
  for (int ii = 0; ii < 4; ++ii) {
    int r = row0 + ty*4 + ii;
    if (r >= M) continue;
    for (int jj = 0; jj < 4; ++jj) {
      int c = col0 + tx*4 + jj;
      if (c < N) C[(long)r*N + c] = acc[ii][jj];
    }
  }
}

// C = A^T B (sub=0) or C -= A^T B (sub=1); A is (K x M) row-major, B is (K x N) row-major
__global__ __launch_bounds__(256) void k_gemm_tn(const float* __restrict__ A, const float* __restrict__ B,
                                                 float* __restrict__ C, int M, int N, int K, int sub) {
  __shared__ float As[16][68];
  __shared__ float Bs[16][68];
  int tid = threadIdx.x, tx = tid % 16, ty = tid / 16;
  int row0 = blockIdx.y*64, col0 = blockIdx.x*64;
  float acc[4][4] = {};
  for (int k0 = 0; k0 < K; k0 += 16) {
    for (int i = tid; i < 16*64; i += 256) {
      int r = i % 64, kk = i / 64;
      float v = 0.f;
      if (k0 + kk < K && row0 + r < M) v = A[(long)(k0+kk)*M + row0 + r];
      As[kk][r] = v;
    }
    for (int i = tid; i < 16*64; i += 256) {
      int c = i % 64, kk = i / 64;
      float v = 0.f;
      if (k0 + kk < K && col0 + c < N) v = B[(long)(k0+kk)*N + col0 + c];
      Bs[kk][c] = v;
    }
    __syncthreads();
    for (int kk = 0; kk < 16; ++kk) {
      float av[4], bv[4];
#pragma unroll
      for (int ii = 0; ii < 4; ++ii) av[ii] = As[kk][ty*4+ii];
#pragma unroll
      for (int jj = 0; jj < 4; ++jj) bv[jj] = Bs[kk][tx*4+jj];
#pragma unroll
      for (int ii = 0; ii < 4; ++ii)
#pragma unroll
        for (int jj = 0; jj < 4; ++jj) acc[ii][jj] += av[ii]*bv[jj];
    }
    __syncthreads();
  }
  for (int ii = 0; ii < 4; ++ii) {
    int r = row0 + ty*4 + ii;
    if (r >= M) continue;
    for (int jj = 0; jj < 4; ++jj) {
      int c = col0 + tx*4 + jj;
      if (c < N) {
        if (sub) C[(long)r*N + c] -= acc[ii][jj];
        else     C[(long)r*N + c]  = acc[ii][jj];
      }
    }
  }
}

// Split-K  Cpart[z] = A(M x K) B(N x K)^T over K-chunk z (128 wide). Tile 32x32, 2x2/thr.
__global__ __launch_bounds__(256) void k_gnt_splitk(const float* __restrict__ A, const float* __restrict__ B,
                                                    float* __restrict__ Cp, int M, int N, int K) {
  __shared__ float As[16][33];
  __shared__ float Bs[16][33];
  int tid = threadIdx.x, tx = tid % 16, ty = tid / 16;
  int row0 = blockIdx.y*32, col0 = blockIdx.x*32;
  int z = blockIdx.z;
  int kbeg = z*128, kend = kbeg + 128 < K ? kbeg + 128 : K;
  float acc[2][2] = {};
  for (int k0 = kbeg; k0 < kend; k0 += 16) {
    for (int i = tid; i < 512; i += 256) {
      int kk = i & 15, r = i >> 4;
      float v = 0.f;
      if (row0 + r < M && k0 + kk < K) v = A[(long)(row0+r)*K + k0 + kk];
      As[kk][r] = v;
    }
    for (int i = tid; i < 512; i += 256) {
      int kk = i & 15, c = i >> 4;
      float v = 0.f;
      if (col0 + c < N && k0 + kk < K) v = B[(long)(col0+c)*K + k0 + kk];
      Bs[kk][c] = v;
    }
    __syncthreads();
    for (int kk = 0; kk < 16; ++kk) {
      float a0 = As[kk][ty*2], a1 = As[kk][ty*2+1];
      float b0 = Bs[kk][tx*2], b1 = Bs[kk][tx*2+1];
      acc[0][0] += a0*b0; acc[0][1] += a0*b1;
      acc[1][0] += a1*b0; acc[1][1] += a1*b1;
    }
    __syncthreads();
  }
  long base = (long)z * M * N;
  for (int ii = 0; ii < 2; ++ii) {
    int r = row0 + ty*2 + ii;
    if (r >= M) continue;
    for (int jj = 0; jj < 2; ++jj) {
      int c = col0 + tx*2 + jj;
      if (c < N) Cp[base + (long)r*N + c] = acc[ii][jj];
    }
  }
}

__global__ void k_reduceK(const float* __restrict__ in, float* __restrict__ out, long mn, int S) {
  for (long i = blockIdx.x * (long)blockDim.x + threadIdx.x; i < mn;
       i += (long)gridDim.x * blockDim.x) {
    float s = 0.f;
    for (int z = 0; z < S; ++z) s += in[(long)z*mn + i];
    out[i] = s;
  }
}

// ---------------- subspace iteration pieces ----------------
__global__ void k_xinit(float* __restrict__ X, int n, unsigned seed) {
  int i = blockIdx.x * blockDim.x + threadIdx.x;
  if (i >= n) return;
  unsigned x = (unsigned)i * 2654435761u + seed;
  x ^= x >> 16; x *= 2246822519u; x ^= x >> 13; x *= 3266489917u; x ^= x >> 16;
  X[i] = (float)x * (1.0f/4294967296.0f) - 0.5f;
}

// CholQR solve step: given Gram G (32x32) of panel P (32 x Nm), compute L = chol(G)
// (redundantly per block, wave-synchronous in wave 0) and apply P <- L^{-1} P for this
// block's 256 columns. Clamped pivots zero their row (rank-deficiency safe).
__global__ __launch_bounds__(256) void k_cholsolve32(float* __restrict__ P,
                                                     const float* __restrict__ Gin, int Nm) {
  __shared__ float G[32][33];
  __shared__ volatile int clampf[32];
  __shared__ float dminS;
  int tid = threadIdx.x, wave = tid >> 6, lane = tid & 63;
  for (int i = tid; i < 1024; i += 256) G[i >> 5][i & 31] = Gin[i];
  __syncthreads();
  if (tid == 0) {
    float tr = 0.f;
    for (int i2 = 0; i2 < 32; ++i2) tr += G[i2][i2];
    dminS = tr * (1e-10f / 32.f) + 1e-30f;
  }
  __syncthreads();
  if (wave == 0) {
    volatile float* Gv = &G[0][0];   // row stride 33
    for (int k = 0; k < 32; ++k) {
      if (lane == 0) {
        float d = Gv[k*33+k];
        int bad = (d < dminS) ? 1 : 0;
        clampf[k] = bad;
        Gv[k*33+k] = sqrtf(bad ? dminS : d);
      }
      __builtin_amdgcn_wave_barrier();
      float lkk = Gv[k*33+k];
      int bad = clampf[k];
      int i2 = k + 1 + lane;
      float lik = 0.f;
      if (i2 < 32) { lik = bad ? 0.f : (Gv[i2*33+k] / lkk); Gv[i2*33+k] = lik; }
      __builtin_amdgcn_wave_barrier();
      for (int j2 = k + 1; j2 < 32; ++j2) {
        float ljk = __shfl(lik, j2 - k - 1);
        if (i2 < 32 && j2 <= i2) Gv[i2*33+j2] -= lik * ljk;
      }
      __builtin_amdgcn_wave_barrier();
    }
  }
  __syncthreads();
  int c = blockIdx.x * 256 + tid;
  if (c < Nm) {
    float v[32];
#pragma unroll
    for (int i2 = 0; i2 < 32; ++i2) v[i2] = P[(long)i2 * Nm + c];
#pragma unroll
    for (int i2 = 0; i2 < 32; ++i2) {
      float s = v[i2];
      for (int j2 = 0; j2 < i2; ++j2) s -= G[i2][j2] * v[j2];
      v[i2] = clampf[i2] ? 0.f : (s / G[i2][i2]);
    }
#pragma unroll
    for (int i2 = 0; i2 < 32; ++i2) P[(long)i2 * Nm + c] = v[i2];
  }
}

// Cyclic Jacobi eigensolver for symmetric 128x128, LDS-resident, early-exit.
// V stored TRANSPOSED in LDS (Vt[p][i] = V[i][p]) so the column-rotation update is
// contiguous per lane -> no 64-way bank conflict (round-4 V update was stride-128).
__global__ __launch_bounds__(1024) void k_jacobi(const float* __restrict__ Bin, float* __restrict__ Vout,
                                                 float* __restrict__ wout, int maxsweeps) {
  const int n = KSUB;
  __shared__ float Bs[KSUB*KSUB];
  __shared__ float Vt[KSUB*KSUB];
  __shared__ float cS[64], sS[64];
  __shared__ int pS[64], qS[64];
  __shared__ float redA[16], redB[16];
  __shared__ int done;
  int tid = threadIdx.x, wave = tid >> 6, lane = tid & 63;
  for (int i = tid; i < n*n; i += 1024) { Bs[i] = Bin[i]; Vt[i] = ((i / n) == (i % n)) ? 1.f : 0.f; }
  if (tid == 0) done = 0;
  __syncthreads();
  for (int sw = 0; sw < maxsweeps; ++sw) {
    for (int r = 0; r < n-1; ++r) {
      if (tid < 64) {
        int k = tid, a, b;
        if (k == 0) { a = n-1; b = r % (n-1); }
        else { a = (r + k) % (n-1); b = (r - k + (n-1)) % (n-1); }
        int p = a < b ? a : b, q = a < b ? b : a;
        float bpp = Bs[p*n+p], bqq = Bs[q*n+q], bpq = Bs[p*n+q];
        float c = 1.f, s = 0.f;
        if (bpq != 0.f) {
          float tau = (bqq - bpp) / (2.f*bpq);
          float t = (tau >= 0.f ? 1.f : -1.f) / (fabsf(tau) + sqrtf(1.f + tau*tau));
          c = rsqrtf(1.f + t*t); s = t*c;
        }
        pS[k] = p; qS[k] = q; cS[k] = c; sS[k] = s;
      }
      __syncthreads();
      for (int t = tid; t < 64*64; t += 1024) {
        int k1 = t >> 6, k2 = t & 63;
        int p1 = pS[k1], q1 = qS[k1]; float c1 = cS[k1], s1 = sS[k1];
        int p2 = pS[k2], q2 = qS[k2]; float c2 = cS[k2], s2 = sS[k2];
        float a = Bs[p1*n+p2], b = Bs[p1*n+q2], d = Bs[q1*n+p2], e = Bs[q1*n+q2];
        float a1 = c1*a - s1*d, b1 = c1*b - s1*e;
        float d1 = s1*a + c1*d, e1 = s1*b + c1*e;
        Bs[p1*n+p2] = c2*a1 - s2*b1; Bs[p1*n+q2] = s2*a1 + c2*b1;
        Bs[q1*n+p2] = c2*d1 - s2*e1; Bs[q1*n+q2] = s2*d1 + c2*e1;
      }
      for (int t = tid; t < 64*n; t += 1024) {
        int k = t >> 7, i = t & (n-1);
        int p = pS[k], q = qS[k]; float c = cS[k], s = sS[k];
        float vp = Vt[p*n+i], vq = Vt[q*n+i];
        Vt[p*n+i] = c*vp - s*vq; Vt[q*n+i] = s*vp + c*vq;
      }
      __syncthreads();
    }
    // convergence check: off-diagonal mass vs diagonal mass (relative)
    float offs = 0.f, dias = 0.f;
    for (int i = tid; i < n*n; i += 1024) {
      float v = Bs[i];
      if ((i / n) == (i % n)) dias += v*v; else offs += v*v;
    }
    for (int o = 32; o; o >>= 1) { offs += __shfl_down(offs, o); dias += __shfl_down(dias, o); }
    if (lane == 0) { redA[wave] = offs; redB[wave] = dias; }
    __syncthreads();
    if (tid == 0) {
      float oa = 0.f, db = 0.f;
      for (int wv = 0; wv < 16; ++wv) { oa += redA[wv]; db += redB[wv]; }
      done = (oa <= 1e-9f * db + 1e-30f) ? 1 : 0;
    }
    __syncthreads();
    if (done) break;
  }
  for (int i = tid; i < n; i += 1024) wout[i] = Bs[i*n+i];
  for (int t = tid; t < n*n; t += 1024) {   // Vout[i][j] = Vt[j][i]
    int i = t >> 7, j = t & (n-1);
    Vout[t] = Vt[j*n+i];
  }
}

// Wave-parallel |w| selection sort: idx[0..n) desc by |w|; ws/wsn over top-k. One wave, n=128.
__global__ void k_select(const float* __restrict__ w, int n, int topk,
                         int* __restrict__ idx, float* __restrict__ ws, float* __restrict__ wsn) {
  int lane = threadIdx.x;   // 64 threads
  float v0 = w[lane], v1 = w[lane + 64];
  float a0 = fabsf(v0), a1 = fabsf(v1);
  float ss = 0.f;
  for (int t = 0; t < n; ++t) {
    float b, bv; int bi;
    if (a0 >= a1) { b = a0; bi = lane; bv = v0; }
    else          { b = a1; bi = lane + 64; bv = v1; }
    for (int o = 32; o; o >>= 1) {
      float ob = __shfl_down(b, o);
      int   oi = __shfl_down(bi, o);
      float ov = __shfl_down(bv, o);
      if (ob > b) { b = ob; bi = oi; bv = ov; }
    }
    bi = __shfl(bi, 0); bv = __shfl(bv, 0);
    if (lane == 0) {
      idx[t] = bi;
      if (t < topk) { ws[t] = bv; ss += bv * bv; }
    }
    if (bi == lane) a0 = -1.f;
    if (bi == lane + 64) a1 = -1.f;
  }
  if (lane == 0) wsn[0] = sqrtf(ss);
}

__global__ void k_setC(float* __restrict__ C, const float* __restrict__ ws,
                       const float* __restrict__ wsn, int chin) {
  int i = blockIdx.x * blockDim.x + threadIdx.x;
  if (i >= chin*chin) return;
  int r = i / chin, c = i % chin;
  C[i] = (r == c) ? ws[r] / wsn[0] : 0.f;
}

__global__ void k_gather(const float* __restrict__ V, const int* __restrict__ idx,
                         float* __restrict__ Vs, int n, int topk) {
  int i = blockIdx.x * blockDim.x + threadIdx.x;
  if (i >= n*topk) return;
  int r = i / topk, a = i % topk;
  Vs[i] = V[r*n + idx[a]];
}

// ---------------- observable stage ----------------
__global__ void k_buildK(const float* __restrict__ As, float* __restrict__ K6) {
  int i = blockIdx.x * blockDim.x + threadIdx.x;
  if (i >= 1024) return;
  int y = i & 3, v = (i>>2)&3, x = (i>>4)&3, u = (i>>6)&3, s = (i>>8)&1, p = (i>>9)&1;
  float acc = 0.f;
  for (int w = 0; w < 4; ++w)
    acc += As[((p*4+u)*4+x)*4+w] * As[((s*4+v)*4+y)*4+w];
  K6[i] = acc;
}

__global__ void k_Y1(const float* __restrict__ K6, const float* __restrict__ S, float* __restrict__ Y1) {
  int i = blockIdx.x * blockDim.x + threadIdx.x;
  if (i >= 1024) return;
  int f = i & 3, e = (i>>2)&3, b = (i>>4)&3, a = (i>>6)&3, s = (i>>8)&1, p = (i>>9)&1;
  float acc = 0.f;
  for (int u = 0; u < 4; ++u)
    for (int x = 0; x < 4; ++x)
      for (int v = 0; v < 4; ++v)
        for (int y = 0; y < 4; ++y)
          acc += K6[((((p*2+s)*4+u)*4+x)*4+v)*4+y]
               * S[(((x*4+b)*16 + (v*4+e))*16 + (y*4+f))*16 + (u*4+a)];
  Y1[i] = acc;
}

__global__ void k_W16(const float* __restrict__ K6, const float* __restrict__ Y1, float* __restrict__ W) {
  int i = threadIdx.x;
  if (i >= 16) return;
  int qr = i >> 2, ps = i & 3;
  float acc = 0.f;
  for (int j = 0; j < 256; ++j) acc += K6[qr*256 + j] * Y1[ps*256 + j];
  W[i] = acc;
}

__global__ void k_final(const float* __restrict__ W, const float* __restrict__ H,
                        const float* __restrict__ Ox, const float* __restrict__ Oy,
                        const float* __restrict__ Oz, float* __restrict__ out) {
  if (threadIdx.x != 0 || blockIdx.x != 0) return;
  float Z = 0.f;
  for (int q = 0; q < 2; ++q)
    for (int r = 0; r < 2; ++r) Z += W[((q*2+r)*2+q)*2+r];
  float ln = 0.f;
  for (int i = 0; i < 16; ++i) ln += H[i]*W[i];
  out[0] = ln / Z;
  const float* Os[3] = {Ox, Oy, Oz};
  for (int k = 0; k < 3; ++k) {
    float vA = 0.f, vB = 0.f;
    for (int q = 0; q < 2; ++q)
      for (int p = 0; p < 2; ++p)
        for (int r = 0; r < 2; ++r)
          vA += Os[k][q*2+p] * W[((q*2+r)*2+p)*2+r];
    for (int q = 0; q < 2; ++q)
      for (int r = 0; r < 2; ++r)
        for (int s = 0; s < 2; ++s)
          vB += Os[k][r*2+s] * W[((q*2+r)*2+q)*2+s];
    out[1+k] = 0.5f*(vA+vB)/Z;
  }
}

// ---------------- host ----------------
static inline unsigned nb256(long n) { long b = (n + 255) / 256; return (unsigned)(b < 1 ? 1 : b); }

extern "C" void kernel_launch(void* const* d_in, const int* in_sizes, int n_in,
                              void* d_out, int out_size, void* d_ws, size_t ws_size,
                              hipStream_t stream) {
  const float* A1  = (const float*)d_in[0];
  const float* Hin = (const float*)d_in[1];
  const float* Ox  = (const float*)d_in[2];
  const float* Oy  = (const float*)d_in[3];
  const float* Oz  = (const float*)d_in[4];

  const long SZ_BIG = 1536L*1536L;
  float* p0 = (float*)d_ws;
  float* Asym = p0; p0 += 128;
  float* Tb   = p0; p0 += 4096;
  float* Mb   = p0; p0 += 65536;
  float* Mp   = p0; p0 += 65536;
  float* Mq   = p0; p0 += 65536;
  float* Ca   = p0; p0 += CHI*CHI;
  float* Cb   = p0; p0 += CHI*CHI;
  float* Ea   = p0; p0 += CHI*D2T*CHI;
  float* Eb   = p0; p0 += CHI*D2T*CHI;
  float* CE   = p0; p0 += CHI*D2T*CHI;
  float* E2   = p0; p0 += CHI*D2T*CHI;
  float* Pb   = p0; p0 += (CHI*D2T)*CHI;
  float* Xa   = p0; p0 += KSUB*(CHI*D2T);
  float* Xb   = p0; p0 += KSUB*(CHI*D2T);
  float* Bsm  = p0; p0 += KSUB*KSUB;
  float* Vsm  = p0; p0 += KSUB*KSUB;
  float* Vsrt = p0; p0 += KSUB*KSUB;
  float* Cf   = p0; p0 += KSUB*32;
  float* G32  = p0; p0 += 1024;
  float* Part = p0; p0 += 12*KSUB*KSUB;   // split-K partials (S<=12, MN<=128*128)
  float* wv   = p0; p0 += KSUB;
  float* wsv  = p0; p0 += KSUB;
  float* wsn  = p0; p0 += 16;
  float* part = p0; p0 += NBRED;
  int*   idx  = (int*)p0; p0 += KSUB;
  float* Vsel = p0; p0 += KSUB*CHI;
  float* K6   = p0; p0 += 1024;
  float* Y1   = p0; p0 += 1024;
  float* W16  = p0; p0 += 16;
  float* tb   = p0; p0 += CHI*D2T*CHI;
  float* ub   = p0; p0 += CHI*D2T*CHI;
  float* Sb   = p0; p0 += 65536;
  float* B1   = p0; p0 += SZ_BIG;
  float* B2   = p0; p0 += SZ_BIG;
  float* B3   = p0; p0 += SZ_BIG;
  if ((size_t)((char*)p0 - (char*)d_ws) > ws_size) return;

  auto normalize = [&](float* a, long n) {
    int nb = (int)((n + 255) / 256); if (nb > NBRED) nb = NBRED;
    k_sumsq<<<nb, 256, 0, stream>>>(a, n, part);
    k_scale_sumsq<<<nb256(n), 256, 0, stream>>>(a, n, part, nb);
  };
  auto gnn = [&](const float* A, const float* B, float* C, int M, int N, int K) {
    dim3 g((N+63)/64, (M+63)/64);
    k_gemm_nn<<<g, 256, 0, stream>>>(A, B, C, M, N, K);
  };
  auto gtn = [&](const float* A, const float* B, float* C, int M, int N, int K, int sub = 0) {
    dim3 g((N+63)/64, (M+63)/64);
    k_gemm_tn<<<g, 256, 0, stream>>>(A, B, C, M, N, K, sub);
  };
  // split-K C = A B^T (deterministic two-stage)
  auto gnt_sk = [&](const float* A, const float* B, float* C, int M, int N, int K) {
    int Sk = (K + 127) / 128;
    dim3 g((N+31)/32, (M+31)/32, Sk);
    k_gnt_splitk<<<g, 256, 0, stream>>>(A, B, Part, M, N, K);
    k_reduceK<<<nb256((long)M*N), 256, 0, stream>>>(Part, C, (long)M*N, Sk);
  };
  // BCGS (panel=32) + CholQR: multi-block Gram (split-K) + multi-block solve
  auto ORTH = [&](float* Y, int Nm, int projPasses, int qrPasses) {
    for (int p = 0; p < 4; ++p) {
      float* panel = Y + (long)p * 32 * Nm;
      if (p > 0) {
        for (int ps = 0; ps < projPasses; ++ps) {
          gnt_sk(Y, panel, Cf, p*32, 32, Nm);       // Cf = Qprev panel^T
          gtn(Cf, Y, panel, 32, Nm, p*32, 1);       // panel -= Cf^T Qprev
        }
      }
      for (int qp = 0; qp < qrPasses; ++qp) {
        gnt_sk(panel, panel, G32, 32, 32, Nm);      // G = panel panel^T
        k_cholsolve32<<<(Nm+255)/256, 256, 0, stream>>>(panel, G32, Nm);
      }
    }
  };

  // ---- Stage A ----
  k_symA<<<1, 128, 0, stream>>>(A1, Asym);
  k_buildT<<<16, 256, 0, stream>>>(Asym, Tb);
  normalize(Tb, 4096);
  k_buildM<<<256, 256, 0, stream>>>(Tb, Mb);
  normalize(Mb, 65536);
  k_perm4<<<256, 256, 0, stream>>>(Mb, Mp, 16,16,16,16, 16L,4096L,256L,1L);   // Mp[(x,u),(v,y)]
  k_perm4<<<256, 256, 0, stream>>>(Mb, Mq, 16,16,16,16, 4096L,16L,256L,1L);   // Mq[(u,x),(v,y)]
  k_initC<<<1, 256, 0, stream>>>(Mb, Ca);
  k_sym2d<<<1, 256, 0, stream>>>(Ca, 16);
  normalize(Ca, 256);
  k_initE<<<16, 256, 0, stream>>>(Mb, Ea);
  k_symE<<<16, 256, 0, stream>>>(Ea, 16);
  normalize(Ea, 4096);

  // ---- CTMRG iterations ----
  const int nqs[NITER] = {8, 8, 4, 3, 3, 2, 2, 2, 2, 2, 2, 3};
  float* Ccur = Ca; float* Calt = Cb;
  float* Ecur = Ea; float* Ealt = Eb;
  float* Xc = Xa; float* Yc = Xb;   // persistent subspace basis (warm-started)
  int chic = 16;
  for (int it = 0; it < NITER; ++it) {
    int Nm = chic * D2T;
    int chin = CHI;
    int passes = (it <= 1 || it == NITER-1) ? 2 : 1;
    // Rho build: m[(i,v),(j,y)]
    gnn(Ccur, Ecur, CE, chic, D2T*chic, chic);                                 // CE[a,(x,i)]
    k_perm4<<<nb256((long)chic*chic*16), 256, 0, stream>>>(Ecur, E2,
        chic, chic, 16, 1, 1L, (long)16*chic, (long)chic, 0L);                 // E2[a,(j,u)]
    gtn(CE, E2, B1, 16*chic, 16*chic, chic);                                   // D1[(x,i),(j,u)]
    k_perm4<<<nb256((long)Nm*Nm), 256, 0, stream>>>(B1, B2,
        chic, chic, 16, 16, (long)16*chic, 16L, (long)chic*16*chic, 1L);       // D1p[(i,j),(x,u)]
    gnn(B2, Mp, B1, chic*chic, 256, 256);                                      // Q[(i,j),(v,y)]
    k_perm4<<<nb256((long)Nm*Nm), 256, 0, stream>>>(B1, B2,
        chic, 16, chic, 16, (long)chic*256, 16L, 256L, 1L);                    // m[(i,v),(j,y)]
    k_sym2d<<<nb256((long)Nm*Nm), 256, 0, stream>>>(B2, Nm);
    float* msym = B2;
    // Subspace iteration for top eigenpairs by |lambda| (warm-started for it>=2)
    int nq = nqs[it];
    if (it <= 1)
      k_xinit<<<nb256((long)KSUB*Nm), 256, 0, stream>>>(Xc, KSUB*Nm, 0x9E3779B9u);
    for (int t = 0; t < nq; ++t) {
      gnn(Xc, msym, Yc, KSUB, Nm, Nm);      // Y = X m  (m symmetric)
      ORTH(Yc, Nm, passes, passes);
      float* tm = Xc; Xc = Yc; Yc = tm;
    }
    gnn(Xc, msym, Yc, KSUB, Nm, Nm);        // Y2 = X m
    gnt_sk(Yc, Xc, Bsm, KSUB, KSUB, Nm);    // B = X m X^T
    k_sym2d<<<nb256((long)KSUB*KSUB), 256, 0, stream>>>(Bsm, KSUB);
    k_jacobi<<<1, 1024, 0, stream>>>(Bsm, Vsm, wv, JSWMAX);
    k_select<<<1, 64, 0, stream>>>(wv, KSUB, chin, idx, wsv, wsn);
    k_setC<<<nb256((long)chin*chin), 256, 0, stream>>>(Calt, wsv, wsn, chin);
    k_gather<<<nb256((long)KSUB*chin), 256, 0, stream>>>(Vsm, idx, Vsel, KSUB, chin);
    gtn(Xc, Vsel, Pb, Nm, chin, KSUB);      // P (Nm x chin) = Ritz vectors
    // Warm start for next iteration: rotate full basis into Ritz order (Nm unchanged for it>=1)
    if (it >= 1 && it < NITER-1) {
      k_gather<<<nb256((long)KSUB*KSUB), 256, 0, stream>>>(Vsm, idx, Vsrt, KSUB, KSUB);
      gtn(Vsrt, Xc, Yc, KSUB, Nm, KSUB);    // Xnew = Vsrt^T Xc
      float* tm = Xc; Xc = Yc; Yc = tm;
    }
    // E update: Enew[a,y,b]
    gtn(Pb, Ecur, B1, D2T*chin, D2T*chic, chic);                               // T1[(u,a),(x,j)]
    k_perm4<<<nb256((long)D2T*chin*D2T*chic), 256, 0, stream>>>(B1, B2,
        chin, chic, 16, 16, (long)16*chic, 1L, (long)chin*16*chic, (long)chic);// T1p[(a,j),(u,x)]
    gnn(B2, Mq, B1, chin*chic, 256, 256);                                      // T2[(a,j),(v,y)]
    k_perm4<<<nb256((long)chin*chic*256), 256, 0, stream>>>(B1, B2,
        chin, 16, chic, 16, (long)chic*256, 1L, 256L, 16L);                    // T2p[(a,y),(j,v)]
    gnn(B2, Pb, Ealt, chin*D2T, chin, chic*D2T);                               // Enew[(a,y),b]
    k_symE<<<nb256((long)chin*16*chin), 256, 0, stream>>>(Ealt, chin);
    normalize(Ealt, (long)chin*16*chin);
    { float* t1 = Ccur; Ccur = Calt; Calt = t1; }
    { float* t1 = Ecur; Ecur = Ealt; Ealt = t1; }
    chic = chin;
  }

  // ---- Environment closure: S_env and observables ----
  gnn(Ccur, Ecur, tb, CHI, D2T*CHI, CHI);                   // t[a,(x,c)]
  gnn(tb, Ccur, ub, CHI*D2T, CHI, CHI);                     // up[(a,x),d]
  gnn(ub, Ecur, B1, CHI*D2T, D2T*CHI, CHI);                 // T1env[(a,x),(v,e)]
  k_perm4<<<nb256(SZ_BIG), 256, 0, stream>>>(B1, B2,
      16, 16, CHI, CHI, 1536L, 96L, 24576L, 1L);            // A'[(X,V),(a,e)]
  k_perm4<<<nb256(SZ_BIG), 256, 0, stream>>>(B1, B3,
      CHI, CHI, 16, 16, 1L, 24576L, 1536L, 96L);            // B'[(a,e),(Y,U)]
  gnn(B2, B3, Sb, 256, 256, CHI*CHI);                       // S[X,V,Y,U]
  k_buildK<<<4, 256, 0, stream>>>(Asym, K6);
  k_Y1<<<4, 256, 0, stream>>>(K6, Sb, Y1);
  k_W16<<<1, 16, 0, stream>>>(K6, Y1, W16);
  k_final<<<1, 1, 0, stream>>>(W16, Hin, Ox, Oy, Oz, (float*)d_out);
}